// Round 9
// baseline (171.566 us; speedup 1.0000x reference)
//
#include <hip/hip_runtime.h>

typedef unsigned short u16;
typedef unsigned int   u32;
typedef short  short8  __attribute__((ext_vector_type(8)));
typedef __bf16 bf16x8  __attribute__((ext_vector_type(8)));
typedef float  f32x4   __attribute__((ext_vector_type(4)));
typedef u32    u32x4   __attribute__((ext_vector_type(4)));

#define POWER_ITERS 3

// ---------- helpers ----------
__device__ __forceinline__ u16 f2bf(float f){ return __builtin_bit_cast(u16, (__bf16)f); }
__device__ __forceinline__ u32 pack2bf(float a, float b){
  return (u32)__builtin_bit_cast(u16, (__bf16)a) | ((u32)__builtin_bit_cast(u16, (__bf16)b) << 16);
}
__device__ __forceinline__ float bf2f(u16 h){ return __uint_as_float(((u32)h) << 16); }

__device__ __forceinline__ f32x4 mfma_bf16(short8 a, short8 b, f32x4 c){
  return __builtin_amdgcn_mfma_f32_16x16x32_bf16(
      __builtin_bit_cast(bf16x8, a), __builtin_bit_cast(bf16x8, b), c, 0, 0, 0);
}

// swizzled LDS address (u16 units) of element [row][k] of a 64x64 matrix
__device__ __forceinline__ int swz(int row, int k){
  return row*64 + ((((k >> 3) ^ (row & 7)) << 3) | (k & 7));
}
__device__ __forceinline__ short8 lds_frag(const u16* P, int row, int k0){
  int pos = (k0 >> 3) ^ (row & 7);
  return *(const short8*)(P + row*64 + pos*8);
}
__device__ __forceinline__ short8 g_frag(const u16* __restrict__ M, int row, int k0){
  return *(const short8*)(M + row*64 + k0);
}

// write C/D regs (matrix X) as X^T into swizzled LDS (Zt), scaled
__device__ __forceinline__ void write_CT_lds_s(u16* Pt, int lane, const f32x4 (&C)[4][4], float s){
  const int m16 = lane & 15, q = lane >> 4;
#pragma unroll
  for(int i = 0; i < 4; i++){
    const int r0 = i*16 + q*4;
#pragma unroll
    for(int j = 0; j < 4; j++){
      const int c = j*16 + m16;
      const int addr = c*64 + ((((r0 >> 3) ^ (c & 7)) << 3) | (r0 & 7));
      u32 lo = pack2bf(C[i][j][0]*s, C[i][j][1]*s);
      u32 hi = pack2bf(C[i][j][2]*s, C[i][j][3]*s);
      *(uint2*)(Pt + addr) = make_uint2(lo, hi);
    }
  }
}
__device__ __forceinline__ void write_CT_lds(u16* Pt, int lane, const f32x4 (&C)[4][4]){
  write_CT_lds_s(Pt, lane, C, 1.f);
}

// write C ROW-MAJOR swizzled (Zn), scaled — scalar scatter
__device__ __forceinline__ void scatter_C_rm(u16* Z, int lane, const f32x4 (&C)[4][4], float s){
  const int m16 = lane & 15, q = lane >> 4;
#pragma unroll
  for(int i = 0; i < 4; i++)
#pragma unroll
    for(int j = 0; j < 4; j++)
#pragma unroll
      for(int t = 0; t < 4; t++)
        Z[swz(i*16 + q*4 + t, j*16 + m16)] = f2bf(C[i][j][t]*s);
}

// C = A (regs) * P (Pt = Zt of P); optional writeback of C^T into Pt
__device__ __forceinline__ void chain_step_A(const short8 (&Af)[2][4], u16* Pt, int lane,
                                             f32x4 (&C)[4][4], bool wb){
  const int m16 = lane & 15, q = lane >> 4;
  short8 Bf[2][4];
#pragma unroll
  for(int ks = 0; ks < 2; ks++)
#pragma unroll
    for(int t = 0; t < 4; t++) Bf[ks][t] = lds_frag(Pt, t*16 + m16, ks*32 + q*8);
#pragma unroll
  for(int i = 0; i < 4; i++)
#pragma unroll
    for(int j = 0; j < 4; j++) C[i][j] = f32x4{0.f,0.f,0.f,0.f};
#pragma unroll
  for(int ks = 0; ks < 2; ks++)
#pragma unroll
    for(int i = 0; i < 4; i++)
#pragma unroll
      for(int j = 0; j < 4; j++)
        C[i][j] = mfma_bf16(Af[ks][i], Bf[ks][j], C[i][j]);
  if(wb) write_CT_lds(Pt, lane, C);
}

__device__ __forceinline__ void ld_zn_frags(const u16* Zn, int m16, int q, short8 (&Af)[2][4]){
#pragma unroll
  for(int ks = 0; ks < 2; ks++)
#pragma unroll
    for(int t = 0; t < 4; t++) Af[ks][t] = lds_frag(Zn, t*16 + m16, ks*32 + q*8);
}
__device__ __forceinline__ void ld_bf16_frags(const u16* __restrict__ M, int m16, int q, short8 (&Af)[2][4]){
#pragma unroll
  for(int ks = 0; ks < 2; ks++)
#pragma unroll
    for(int t = 0; t < 4; t++) Af[ks][t] = g_frag(M, t*16 + m16, ks*32 + q*8);
}
// A-frags (rows) from row-major fp32 global, fused convert
__device__ __forceinline__ void ld_cvt_frags(const float* __restrict__ Kp, int m16, int q, short8 (&Af)[2][4]){
#pragma unroll
  for(int ks = 0; ks < 2; ks++)
#pragma unroll
    for(int t = 0; t < 4; t++){
      const float* p = Kp + (t*16 + m16)*64 + ks*32 + q*8;
      float4 a = *(const float4*)p, b = *(const float4*)(p + 4);
      u32x4 u = { pack2bf(a.x,a.y), pack2bf(a.z,a.w), pack2bf(b.x,b.y), pack2bf(b.z,b.w) };
      Af[ks][t] = __builtin_bit_cast(short8, u);
    }
}
// A-frags of K^T (i.e. columns of K) from row-major fp32 global, scalar gather
__device__ __forceinline__ void ld_cvt_colfrags(const float* __restrict__ Kp, int m16, int q, short8 (&Af)[2][4]){
#pragma unroll
  for(int ks = 0; ks < 2; ks++)
#pragma unroll
    for(int t = 0; t < 4; t++){
      short8 v;
#pragma unroll
      for(int j = 0; j < 8; j++) v[j] = (short)f2bf(Kp[(ks*32 + q*8 + j)*64 + t*16 + m16]);
      Af[ks][t] = v;
    }
}

// P = N (global row-major bf16) -> Zt of P
__device__ __forceinline__ void load_Pt_transpose(const u16* __restrict__ N, u16* Pt, int lane){
#pragma unroll
  for(int g = 0; g < 8; g++){
    short8 v = *(const short8*)(N + lane*64 + g*8);
#pragma unroll
    for(int t = 0; t < 8; t++) Pt[swz(g*8 + t, lane)] = (u16)v[t];
  }
}
// P = N (global row-major fp32) -> Zt of P (bf16)
__device__ __forceinline__ void load_Pt_transpose_f32(const float* __restrict__ N, u16* Pt, int lane){
#pragma unroll
  for(int g = 0; g < 8; g++){
    float4 a = *(const float4*)(N + lane*64 + g*8);
    float4 b = *(const float4*)(N + lane*64 + g*8 + 4);
    Pt[swz(g*8 + 0, lane)] = f2bf(a.x); Pt[swz(g*8 + 1, lane)] = f2bf(a.y);
    Pt[swz(g*8 + 2, lane)] = f2bf(a.z); Pt[swz(g*8 + 3, lane)] = f2bf(a.w);
    Pt[swz(g*8 + 4, lane)] = f2bf(b.x); Pt[swz(g*8 + 5, lane)] = f2bf(b.y);
    Pt[swz(g*8 + 6, lane)] = f2bf(b.z); Pt[swz(g*8 + 7, lane)] = f2bf(b.w);
  }
}

__device__ __forceinline__ float wave_max(float mx){
  for(int off = 32; off; off >>= 1) mx = fmaxf(mx, __shfl_xor(mx, off, 64));
  return mx;
}
__device__ __forceinline__ int norm_es(const f32x4 (&C)[4][4], float& s){
  float mx = 0.f;
#pragma unroll
  for(int i = 0; i < 4; i++)
#pragma unroll
    for(int j = 0; j < 4; j++)
#pragma unroll
      for(int t = 0; t < 4; t++) mx = fmaxf(mx, C[i][j][t]);   // entries all positive
  mx = wave_max(mx);
  int e; (void)frexpf(mx, &e);
  s = ldexpf(1.f, -e);
  return e;
}

// ---------- coherent partial barriers (agent-scope: per-XCD L2 not coherent) ----------
__device__ __forceinline__ void arrive(int* c){
  __syncthreads();
  if(threadIdx.x == 0){
    __threadfence();
    __hip_atomic_fetch_add(c, 1, __ATOMIC_RELEASE, __HIP_MEMORY_SCOPE_AGENT);
  }
}
__device__ __forceinline__ void wait_ge(int* c, int target){
  if(threadIdx.x == 0){
    while(__hip_atomic_load(c, __ATOMIC_ACQUIRE, __HIP_MEMORY_SCOPE_AGENT) < target)
      __builtin_amdgcn_s_sleep(2);
    __threadfence();
  }
  __syncthreads();
}

// ==================== single kernel, 514 blocks x 256 threads, 3 blocks/CU ====================
// b 2..513: phase A (node b-2: 32 seq-mats, 4 waves x chain-8 + combine) -> Nbuf, arrive c1.
//           b 2..17 additionally: wait c1==512, combine 32 nodes -> M2buf[b-2], arrive c2.
// b 0: power-right, then wait c2==17, final combine + contraction -> out.
// b 1: power-left + lambda, arrive c2.
__global__ __launch_bounds__(256, 3) void kall(const float* __restrict__ K, const int* __restrict__ seq,
                                               u16* __restrict__ Nbuf, u16* __restrict__ M2buf,
                                               int* __restrict__ Sarr, int* __restrict__ Earr,
                                               float* __restrict__ rhoR, float* __restrict__ rhoL,
                                               float* __restrict__ muv, int* __restrict__ bar,
                                               float* __restrict__ outp){
  __shared__ __align__(16) u16 zones[4*4096];
  __shared__ __align__(16) u16 rhoZ[4096];
  __shared__ float redf[4];
  __shared__ int exps[4];
  __shared__ float sh_t2;
  __shared__ int sh_S;
  const int tid = threadIdx.x, lane = tid & 63, wave = tid >> 6, b = blockIdx.x;
  const int m16 = lane & 15, q = lane >> 4;
  u16* zw = zones + wave*4096;

  if(b >= 2){
    // ================= PHASE A =================
    const int pb = b - 2;
    int sv = (lane < 8) ? seq[pb*32 + wave*8 + lane] : 0;
    int s0 = __shfl(sv, 0, 64);
    load_Pt_transpose_f32(K + (size_t)s0*4096, zw, lane);
    f32x4 C[4][4];
    short8 Af[2][4];
#pragma unroll 1
    for(int j = 1; j < 8; j++){
      int sj = __shfl(sv, j, 64);
      ld_cvt_frags(K + (size_t)sj*4096, m16, q, Af);
      chain_step_A(Af, zw, lane, C, j < 7);
    }
    { float s; int e = norm_es(C, s);
      if(!(wave & 1)) write_CT_lds_s(zw, lane, C, s);
      else            scatter_C_rm(zw, lane, C, s);
      if(lane == 0) exps[wave] = e; }
    __syncthreads();
    if(wave < 2){                                  // combine L1
      short8 Aa[2][4]; f32x4 Y[4][4];
      ld_zn_frags(zones + (2*wave + 1)*4096, m16, q, Aa);
      chain_step_A(Aa, zones + 2*wave*4096, lane, Y, wave == 0);
      if(wave == 1) scatter_C_rm(zones + 2*4096, lane, Y, 1.f);
    }
    __syncthreads();
    if(wave == 0){                                 // combine L2 + norm
      short8 Aa[2][4]; f32x4 M[4][4];
      ld_zn_frags(zones + 2*4096, m16, q, Aa);
      chain_step_A(Aa, zones, lane, M, false);
      float sr; int er = norm_es(M, sr);
      scatter_C_rm(zones, lane, M, sr);
      if(lane == 0) Sarr[pb] = er + exps[0] + exps[1] + exps[2] + exps[3];
    }
    __syncthreads();
    { int row = tid >> 2, c0 = (tid & 3)*16;
      u16* out = Nbuf + (size_t)pb*4096 + row*64 + c0;
      *(short8*)out       = lds_frag(zones, row, c0);
      *(short8*)(out + 8) = lds_frag(zones, row, c0 + 8); }
    arrive(bar);                                   // c1

    if(b < 18){
      // ================= COMBINE (32 nodes -> 1) =================
      wait_ge(bar, 512);
      const int idx = b - 2, nb = idx*32;
      load_Pt_transpose(Nbuf + (size_t)(nb + wave*8)*4096, zw, lane);
      f32x4 C2[4][4];
      short8 Af2[2][4];
#pragma unroll 1
      for(int j = 1; j < 8; j++){
        ld_bf16_frags(Nbuf + (size_t)(nb + wave*8 + j)*4096, m16, q, Af2);
        chain_step_A(Af2, zw, lane, C2, j < 7);
      }
      { float s; int e = norm_es(C2, s);
        if(!(wave & 1)) write_CT_lds_s(zw, lane, C2, s);
        else            scatter_C_rm(zw, lane, C2, s);
        if(lane == 0) exps[wave] = e; }
      __syncthreads();
      if(wave < 2){
        short8 Aa[2][4]; f32x4 Y[4][4];
        ld_zn_frags(zones + (2*wave + 1)*4096, m16, q, Aa);
        chain_step_A(Aa, zones + 2*wave*4096, lane, Y, wave == 0);
        if(wave == 1) scatter_C_rm(zones + 2*4096, lane, Y, 1.f);
      }
      __syncthreads();
      if(wave == 0){
        short8 Aa[2][4]; f32x4 M[4][4];
        ld_zn_frags(zones + 2*4096, m16, q, Aa);
        chain_step_A(Aa, zones, lane, M, false);
        float sr; int er = norm_es(M, sr);
        scatter_C_rm(zones, lane, M, sr);
        if(lane == 0) Earr[idx] = er + exps[0] + exps[1] + exps[2] + exps[3];
      }
      __syncthreads();
      { int row = tid >> 2, c0 = (tid & 3)*16;
        u16* out = M2buf + (size_t)idx*4096 + row*64 + c0;
        *(short8*)out       = lds_frag(zones, row, c0);
        *(short8*)(out + 8) = lds_frag(zones, row, c0 + 8); }
      arrive(bar + 1);                             // c2
    }
  } else {
    // ================= POWER (b=0 right, b=1 left) =================
    const bool left = (b == 1);
    short8 Kf0[2][4];
    if(!left) ld_cvt_frags   (K + (size_t)wave*4096, m16, q, Kf0);
    else      ld_cvt_colfrags(K + (size_t)wave*4096, m16, q, Kf0);

    const int row = tid >> 2, k0 = (tid & 3)*16;
    const int pos0 = row*64 + ((( (k0 >> 3)      ) ^ (row & 7)) << 3);
    const int pos1 = row*64 + ((( (k0 >> 3) | 1  ) ^ (row & 7)) << 3);
    { short8 b0, b1;
#pragma unroll
      for(int j = 0; j < 8; j++){
        b0[j] = (row == k0 + j)     ? (short)f2bf(1.f/64.f) : (short)0;
        b1[j] = (row == k0 + 8 + j) ? (short)f2bf(1.f/64.f) : (short)0;
      }
      *(short8*)(rhoZ + pos0) = b0;
      *(short8*)(rhoZ + pos1) = b1; }
    __syncthreads();

    const float S13 = 1.f/8192.f;                  // fixed per-iter scale (lambda ~ 2^13)
#pragma unroll 1
    for(int it = 0; it < POWER_ITERS; it++){
      float v[16];
#pragma unroll
      for(int j = 0; j < 16; j++) v[j] = 0.f;
#pragma unroll 1
      for(int rep = 0; rep < 2; rep++){
        short8 Kf[2][4];
        if(rep == 0){
#pragma unroll
          for(int ks = 0; ks < 2; ks++)
#pragma unroll
            for(int t = 0; t < 4; t++) Kf[ks][t] = Kf0[ks][t];
        } else {
          if(!left) ld_cvt_frags   (K + (size_t)(wave + 4)*4096, m16, q, Kf);
          else      ld_cvt_colfrags(K + (size_t)(wave + 4)*4096, m16, q, Kf);
        }
        f32x4 C[4][4];
        short8 Ar[2][4];
#pragma unroll
        for(int ks = 0; ks < 2; ks++)
#pragma unroll
          for(int t = 0; t < 4; t++) Ar[ks][t] = lds_frag(rhoZ, t*16 + m16, ks*32 + q*8);
#pragma unroll
        for(int i = 0; i < 4; i++)
#pragma unroll
          for(int j = 0; j < 4; j++) C[i][j] = f32x4{0.f,0.f,0.f,0.f};
#pragma unroll
        for(int ks = 0; ks < 2; ks++)
#pragma unroll
          for(int i = 0; i < 4; i++)
#pragma unroll
            for(int j = 0; j < 4; j++)
              C[i][j] = mfma_bf16(Ar[ks][i], Kf[ks][j], C[i][j]);   // rho * Kdir^T
        write_CT_lds(zw, lane, C);
        short8 Bt[2][4];
#pragma unroll
        for(int ks = 0; ks < 2; ks++)
#pragma unroll
          for(int t = 0; t < 4; t++) Bt[ks][t] = lds_frag(zw, t*16 + m16, ks*32 + q*8);
#pragma unroll
        for(int i = 0; i < 4; i++)
#pragma unroll
          for(int j = 0; j < 4; j++) C[i][j] = f32x4{0.f,0.f,0.f,0.f};
#pragma unroll
        for(int ks = 0; ks < 2; ks++)
#pragma unroll
          for(int i = 0; i < 4; i++)
#pragma unroll
            for(int j = 0; j < 4; j++)
              C[i][j] = mfma_bf16(Kf[ks][i], Bt[ks][j], C[i][j]);   // Kdir * (..)^T
        write_CT_lds(zw, lane, C);                 // zone_w = term (symmetric)
        __syncthreads();
        for(int z = 0; z < 4; z++){
          short8 f0 = lds_frag(zones + z*4096, row, k0);
          short8 f1 = lds_frag(zones + z*4096, row, k0 + 8);
#pragma unroll
          for(int j = 0; j < 8; j++){ v[j] += bf2f((u16)f0[j]); v[8 + j] += bf2f((u16)f1[j]); }
        }
        __syncthreads();
      }
      if(it != POWER_ITERS - 1){
        u32x4 u0 = { pack2bf(v[0]*S13, v[1]*S13),  pack2bf(v[2]*S13, v[3]*S13),
                     pack2bf(v[4]*S13, v[5]*S13),  pack2bf(v[6]*S13, v[7]*S13) };
        u32x4 u1 = { pack2bf(v[8]*S13, v[9]*S13),  pack2bf(v[10]*S13, v[11]*S13),
                     pack2bf(v[12]*S13, v[13]*S13),pack2bf(v[14]*S13, v[15]*S13) };
        *(short8*)(rhoZ + pos0) = __builtin_bit_cast(short8, u0);
        *(short8*)(rhoZ + pos1) = __builtin_bit_cast(short8, u1);
        __syncthreads();
      } else {
        float pd = (k0 <= row && row < k0 + 16) ? v[row - k0] : 0.f;
        for(int off = 32; off; off >>= 1) pd += __shfl_xor(pd, off, 64);
        if(lane == 0) redf[wave] = pd;
        __syncthreads();
        float tr = redf[0] + redf[1] + redf[2] + redf[3];
        float inv = 1.f / tr;
        u32x4 u0 = { pack2bf(v[0]*inv, v[1]*inv),  pack2bf(v[2]*inv, v[3]*inv),
                     pack2bf(v[4]*inv, v[5]*inv),  pack2bf(v[6]*inv, v[7]*inv) };
        u32x4 u1 = { pack2bf(v[8]*inv, v[9]*inv),  pack2bf(v[10]*inv, v[11]*inv),
                     pack2bf(v[12]*inv, v[13]*inv),pack2bf(v[14]*inv, v[15]*inv) };
        *(short8*)(rhoZ + pos0) = __builtin_bit_cast(short8, u0);
        *(short8*)(rhoZ + pos1) = __builtin_bit_cast(short8, u1);
        float* ro = left ? rhoL : rhoR;
#pragma unroll
        for(int j = 0; j < 16; j++) ro[row*64 + k0 + j] = v[j]*inv;
        __syncthreads();
      }
    }

    if(left){
      // lambda = tr(rho_l_hat * sum_a K_a K_a^T); wave handles ops {wave, wave+4}
      f32x4 G[4][4];
#pragma unroll
      for(int i = 0; i < 4; i++)
#pragma unroll
        for(int j = 0; j < 4; j++) G[i][j] = f32x4{0.f,0.f,0.f,0.f};
#pragma unroll 1
      for(int rep = 0; rep < 2; rep++){
        short8 Ka[2][4];
        ld_cvt_frags(K + (size_t)(wave + rep*4)*4096, m16, q, Ka);   // rows
#pragma unroll
        for(int ks = 0; ks < 2; ks++)
#pragma unroll
          for(int i = 0; i < 4; i++)
#pragma unroll
            for(int j = 0; j < 4; j++)
              G[i][j] = mfma_bf16(Ka[ks][i], Ka[ks][j], G[i][j]);   // K K^T
      }
      float lp = 0.f;
#pragma unroll
      for(int i = 0; i < 4; i++)
#pragma unroll
        for(int j = 0; j < 4; j++)
#pragma unroll
          for(int t = 0; t < 4; t++){
            int r = i*16 + q*4 + t, c = j*16 + m16;
            lp += G[i][j][t] * bf2f(rhoZ[swz(r, c)]);
          }
      for(int off = 32; off; off >>= 1) lp += __shfl_xor(lp, off, 64);
      if(lane == 0) redf[wave] = lp;
      __syncthreads();
      if(tid == 0) muv[0] = redf[0] + redf[1] + redf[2] + redf[3];
      arrive(bar + 1);                             // c2
    } else {
      // ================= FINAL (block 0) =================
      wait_ge(bar + 1, 17);
      // chains: wave w: X_w = M2[4w+3]*...*M2[4w]
      load_Pt_transpose(M2buf + (size_t)(wave*4)*4096, zw, lane);
      f32x4 C[4][4];
      short8 Af[2][4];
#pragma unroll 1
      for(int j = 1; j < 4; j++){
        ld_bf16_frags(M2buf + (size_t)(wave*4 + j)*4096, m16, q, Af);
        chain_step_A(Af, zw, lane, C, j < 3);
      }
      { float s; int e = norm_es(C, s);
        if(!(wave & 1)) write_CT_lds_s(zw, lane, C, s);
        else            scatter_C_rm(zw, lane, C, s);
        if(lane == 0) exps[wave] = e; }
      __syncthreads();
      if(wave < 2){                                // L1 + side jobs
        short8 Aa[2][4]; f32x4 Y[4][4];
        ld_zn_frags(zones + (2*wave + 1)*4096, m16, q, Aa);
        chain_step_A(Aa, zones + 2*wave*4096, lane, Y, wave == 0);
        if(wave == 1) scatter_C_rm(zones + 2*4096, lane, Y, 1.f);
      } else if(wave == 2){
        float t2 = 0.f;
        for(int j = 0; j < 64; j++){
          int idx = lane + 64*j;
          t2 += rhoR[idx] * rhoL[idx];
        }
        for(int off = 32; off; off >>= 1) t2 += __shfl_xor(t2, off, 64);
        if(lane == 0) sh_t2 = t2;
      } else {
        int s = 0;
#pragma unroll
        for(int kk = 0; kk < 8; kk++) s += Sarr[lane + 64*kk];
        if(lane < 16) s += Earr[lane];
        for(int off = 32; off; off >>= 1) s += __shfl_xor(s, off, 64);
        if(lane == 0) sh_S = s;
      }
      __syncthreads();
      int eM = 0;
      if(wave == 0){                               // L2 -> M in z1 (Zn)
        short8 Aa[2][4];
        ld_zn_frags(zones + 2*4096, m16, q, Aa);
        chain_step_A(Aa, zones, lane, C, false);
        float sM; eM = norm_es(C, sM);
        scatter_C_rm(zones + 1*4096, lane, C, sM);
      } else if(wave == 1){                        // rho_l fp32 -> z3 (Zn bf16)
#pragma unroll
        for(int g = 0; g < 8; g++){
          const float* p = rhoL + lane*64 + g*8;
          float4 a = *(const float4*)p, c = *(const float4*)(p + 4);
          u32x4 u = { pack2bf(a.x,a.y), pack2bf(a.z,a.w), pack2bf(c.x,c.y), pack2bf(c.z,c.w) };
          *(short8*)(zones + 3*4096 + lane*64 + ((g ^ (lane & 7)) << 3)) = __builtin_bit_cast(short8, u);
        }
      }
      __syncthreads();
      if(wave == 0){
        // U = M * rho_r -> z0 (Zt);  D2 = rho_l * U;  t1 = sum D2 .* M
        u16* Pm = zones + 1*4096;
        short8 Ua[2][4], Ub[2][4];
        ld_zn_frags(Pm, m16, q, Ua);
        ld_zn_frags(rhoZ, m16, q, Ub);             // rho_r bf16 (symmetric)
#pragma unroll
        for(int i = 0; i < 4; i++)
#pragma unroll
          for(int j = 0; j < 4; j++) C[i][j] = f32x4{0.f,0.f,0.f,0.f};
#pragma unroll
        for(int ks = 0; ks < 2; ks++)
#pragma unroll
          for(int i = 0; i < 4; i++)
#pragma unroll
            for(int j = 0; j < 4; j++)
              C[i][j] = mfma_bf16(Ua[ks][i], Ub[ks][j], C[i][j]);
        write_CT_lds(zones, lane, C);
        ld_zn_frags(zones + 3*4096, m16, q, Ua);   // rho_l
#pragma unroll
        for(int ks = 0; ks < 2; ks++)
#pragma unroll
          for(int t = 0; t < 4; t++) Ub[ks][t] = lds_frag(zones, t*16 + m16, ks*32 + q*8);
#pragma unroll
        for(int i = 0; i < 4; i++)
#pragma unroll
          for(int j = 0; j < 4; j++) C[i][j] = f32x4{0.f,0.f,0.f,0.f};
#pragma unroll
        for(int ks = 0; ks < 2; ks++)
#pragma unroll
          for(int i = 0; i < 4; i++)
#pragma unroll
            for(int j = 0; j < 4; j++)
              C[i][j] = mfma_bf16(Ua[ks][i], Ub[ks][j], C[i][j]);
        float part = 0.f;
#pragma unroll
        for(int i = 0; i < 4; i++)
#pragma unroll
          for(int j = 0; j < 4; j++)
#pragma unroll
            for(int t = 0; t < 4; t++){
              int r = i*16 + q*4 + t, c = j*16 + m16;
              part += C[i][j][t] * bf2f(Pm[swz(r, c)]);
            }
        for(int off = 32; off; off >>= 1) part += __shfl_xor(part, off, 64);
        if(lane == 0){
          double t1  = (double)part;
          double lam = (double)muv[0];
          double S   = (double)sh_S + eM + exps[0] + exps[1] + exps[2] + exps[3];
          double logp = 16384.0*log2(lam) - 2.0*S - log2(t1) + log2((double)sh_t2);
          outp[0] = (float)logp;
        }
      }
    }
  }
}

// ---------- launch ----------
extern "C" void kernel_launch(void* const* d_in, const int* in_sizes, int n_in,
                              void* d_out, int out_size, void* d_ws, size_t ws_size,
                              hipStream_t stream) {
  const float* K  = (const float*)d_in[0];   // (8,64,64) fp32
  const int* seq  = (const int*)d_in[1];     // (16384,) int32
  char* ws = (char*)d_ws;
  u16*   Nbuf  = (u16*)(ws);                   // 512 * 8KB = 4 MB
  u16*   M2buf = (u16*)(ws + 4194304);         // 16 * 8KB = 128 KB
  int*   Sarr  = (int*)(ws + 4325376);         // 512 ints
  int*   Earr  = (int*)(ws + 4327424);         // 16 ints
  float* rhoR  = (float*)(ws + 4327936);       // 16 KB
  float* rhoL  = (float*)(ws + 4344320);       // 16 KB
  float* muv   = (float*)(ws + 4360704);       // 1 float
  int*   bar   = (int*)(ws + 4360768);         // 2 ints (c1, c2)

  hipMemsetAsync(bar, 0, 8, stream);
  kall<<<514, 256, 0, stream>>>(K, seq, Nbuf, M2buf, Sarr, Earr, rhoR, rhoL, muv, bar,
                                (float*)d_out);
}

// Round 10
// 110.518 us; speedup vs baseline: 1.5524x; 1.5524x over previous
//
#include <hip/hip_runtime.h>

typedef unsigned short u16;
typedef unsigned int   u32;
typedef short  short8  __attribute__((ext_vector_type(8)));
typedef __bf16 bf16x8  __attribute__((ext_vector_type(8)));
typedef float  f32x4   __attribute__((ext_vector_type(4)));
typedef u32    u32x4   __attribute__((ext_vector_type(4)));

#define POWER_ITERS 3

// ---------- helpers ----------
__device__ __forceinline__ u16 f2bf(float f){ return __builtin_bit_cast(u16, (__bf16)f); }
__device__ __forceinline__ u32 pack2bf(float a, float b){
  return (u32)__builtin_bit_cast(u16, (__bf16)a) | ((u32)__builtin_bit_cast(u16, (__bf16)b) << 16);
}
__device__ __forceinline__ float bf2f(u16 h){ return __uint_as_float(((u32)h) << 16); }

__device__ __forceinline__ f32x4 mfma_bf16(short8 a, short8 b, f32x4 c){
  return __builtin_amdgcn_mfma_f32_16x16x32_bf16(
      __builtin_bit_cast(bf16x8, a), __builtin_bit_cast(bf16x8, b), c, 0, 0, 0);
}

// swizzled LDS address (u16 units) of element [row][k] of a 64x64 matrix
__device__ __forceinline__ int swz(int row, int k){
  return row*64 + ((((k >> 3) ^ (row & 7)) << 3) | (k & 7));
}
__device__ __forceinline__ short8 lds_frag(const u16* P, int row, int k0){
  int pos = (k0 >> 3) ^ (row & 7);
  return *(const short8*)(P + row*64 + pos*8);
}
__device__ __forceinline__ short8 g_frag(const u16* __restrict__ M, int row, int k0){
  return *(const short8*)(M + row*64 + k0);
}

// write C/D regs (matrix X) as X^T into swizzled LDS (Zt), scaled
__device__ __forceinline__ void write_CT_lds_s(u16* Pt, int lane, const f32x4 (&C)[4][4], float s){
  const int m16 = lane & 15, q = lane >> 4;
#pragma unroll
  for(int i = 0; i < 4; i++){
    const int r0 = i*16 + q*4;
#pragma unroll
    for(int j = 0; j < 4; j++){
      const int c = j*16 + m16;
      const int addr = c*64 + ((((r0 >> 3) ^ (c & 7)) << 3) | (r0 & 7));
      u32 lo = pack2bf(C[i][j][0]*s, C[i][j][1]*s);
      u32 hi = pack2bf(C[i][j][2]*s, C[i][j][3]*s);
      *(uint2*)(Pt + addr) = make_uint2(lo, hi);
    }
  }
}
__device__ __forceinline__ void write_CT_lds(u16* Pt, int lane, const f32x4 (&C)[4][4]){
  write_CT_lds_s(Pt, lane, C, 1.f);
}

// write C ROW-MAJOR swizzled (Zn), scaled — scalar scatter
__device__ __forceinline__ void scatter_C_rm(u16* Z, int lane, const f32x4 (&C)[4][4], float s){
  const int m16 = lane & 15, q = lane >> 4;
#pragma unroll
  for(int i = 0; i < 4; i++)
#pragma unroll
    for(int j = 0; j < 4; j++)
#pragma unroll
      for(int t = 0; t < 4; t++)
        Z[swz(i*16 + q*4 + t, j*16 + m16)] = f2bf(C[i][j][t]*s);
}

// C = A (regs) * P (Pt = Zt of P); optional writeback of C^T into Pt
__device__ __forceinline__ void chain_step_A(const short8 (&Af)[2][4], u16* Pt, int lane,
                                             f32x4 (&C)[4][4], bool wb){
  const int m16 = lane & 15, q = lane >> 4;
  short8 Bf[2][4];
#pragma unroll
  for(int ks = 0; ks < 2; ks++)
#pragma unroll
    for(int t = 0; t < 4; t++) Bf[ks][t] = lds_frag(Pt, t*16 + m16, ks*32 + q*8);
#pragma unroll
  for(int i = 0; i < 4; i++)
#pragma unroll
    for(int j = 0; j < 4; j++) C[i][j] = f32x4{0.f,0.f,0.f,0.f};
#pragma unroll
  for(int ks = 0; ks < 2; ks++)
#pragma unroll
    for(int i = 0; i < 4; i++)
#pragma unroll
      for(int j = 0; j < 4; j++)
        C[i][j] = mfma_bf16(Af[ks][i], Bf[ks][j], C[i][j]);
  if(wb) write_CT_lds(Pt, lane, C);
}

__device__ __forceinline__ void ld_zn_frags(const u16* Zn, int m16, int q, short8 (&Af)[2][4]){
#pragma unroll
  for(int ks = 0; ks < 2; ks++)
#pragma unroll
    for(int t = 0; t < 4; t++) Af[ks][t] = lds_frag(Zn, t*16 + m16, ks*32 + q*8);
}
__device__ __forceinline__ void ld_bf16_frags(const u16* __restrict__ M, int m16, int q, short8 (&Af)[2][4]){
#pragma unroll
  for(int ks = 0; ks < 2; ks++)
#pragma unroll
    for(int t = 0; t < 4; t++) Af[ks][t] = g_frag(M, t*16 + m16, ks*32 + q*8);
}

// P = N (global row-major bf16) -> Zt of P
__device__ __forceinline__ void load_Pt_transpose(const u16* __restrict__ N, u16* Pt, int lane){
#pragma unroll
  for(int g = 0; g < 8; g++){
    short8 v = *(const short8*)(N + lane*64 + g*8);
#pragma unroll
    for(int t = 0; t < 8; t++) Pt[swz(g*8 + t, lane)] = (u16)v[t];
  }
}
// Pt <- Zt of an LDS Zn zone
__device__ __forceinline__ void lds_transpose(const u16* Z, u16* Pt, int lane){
#pragma unroll
  for(int g = 0; g < 8; g++){
    short8 f = lds_frag(Z, lane, g*8);
#pragma unroll
    for(int j = 0; j < 8; j++) Pt[swz(g*8 + j, lane)] = (u16)f[j];
  }
}

__device__ __forceinline__ float wave_max(float mx){
  for(int off = 32; off; off >>= 1) mx = fmaxf(mx, __shfl_xor(mx, off, 64));
  return mx;
}
__device__ __forceinline__ int norm_es(const f32x4 (&C)[4][4], float& s){
  float mx = 0.f;
#pragma unroll
  for(int i = 0; i < 4; i++)
#pragma unroll
    for(int j = 0; j < 4; j++)
#pragma unroll
      for(int t = 0; t < 4; t++) mx = fmaxf(mx, C[i][j][t]);   // entries all positive
  mx = wave_max(mx);
  int e; (void)frexpf(mx, &e);
  s = ldexpf(1.f, -e);
  return e;
}

// ---------- coherent partial barriers (agent-scope: per-XCD L2 not coherent) ----------
__device__ __forceinline__ void arrive(int* c){
  __syncthreads();
  if(threadIdx.x == 0){
    __threadfence();
    __hip_atomic_fetch_add(c, 1, __ATOMIC_RELEASE, __HIP_MEMORY_SCOPE_AGENT);
  }
}
__device__ __forceinline__ void wait_ge(int* c, int target){
  if(threadIdx.x == 0){
    while(__hip_atomic_load(c, __ATOMIC_ACQUIRE, __HIP_MEMORY_SCOPE_AGENT) < target)
      __builtin_amdgcn_s_sleep(2);
    __threadfence();
  }
  __syncthreads();
}

// ==================== single kernel: 256 blocks x 512 threads, 1 block/CU ====================
// all blocks: stage K->LDS; blocks 0,1 run power first (b1 also lambda), then EVERY block
// computes node b (64 seq-mats: 8 waves x chain-8 + 3 combine rounds) -> Nbuf[b], arrive c1.
// blocks 2..17: wait c1>=256, combine 16 nodes -> M2buf[b-2], arrive c2. block 1: arrive c2.
// block 0: wait c2>=17, final 16->1 combine + contraction -> out.
__global__ __launch_bounds__(512) void kall(const float* __restrict__ K, const int* __restrict__ seq,
                                            u16* __restrict__ Nbuf, u16* __restrict__ M2buf,
                                            int* __restrict__ Sarr, int* __restrict__ Earr,
                                            float* __restrict__ rhoR, float* __restrict__ rhoL,
                                            float* __restrict__ muv, int* __restrict__ bar,
                                            float* __restrict__ outp){
  __shared__ __align__(16) u16 Kl[8*4096];     // bf16 K (Zn swizzled)
  __shared__ __align__(16) u16 zones[8*4096];
  __shared__ __align__(16) u16 rhoZ[4096];
  __shared__ float redf[8];
  __shared__ int exps[8];
  __shared__ float sh_t2;
  __shared__ int sh_S;
  const int tid = threadIdx.x, lane = tid & 63, wave = tid >> 6, b = blockIdx.x;
  const int m16 = lane & 15, q = lane >> 4;
  u16* zw = zones + wave*4096;

  // stage K[wave] fp32 -> Kl (Zn swizzled); lane owns row = lane
#pragma unroll
  for(int g = 0; g < 8; g++){
    const float* p = K + (size_t)wave*4096 + lane*64 + g*8;
    float4 a = *(const float4*)p, c = *(const float4*)(p + 4);
    u32x4 u = { pack2bf(a.x,a.y), pack2bf(a.z,a.w), pack2bf(c.x,c.y), pack2bf(c.z,c.w) };
    *(short8*)(Kl + wave*4096 + lane*64 + ((g ^ (lane & 7)) << 3)) = __builtin_bit_cast(short8, u);
  }
  int sv = (lane < 8) ? seq[b*64 + wave*8 + lane] : 0;
  __syncthreads();

  if(b < 2){
    // ================= POWER (b0: right, b1: left) =================
    const bool left = (b == 1);
    short8 Kf[2][4];
    if(!left){
      ld_zn_frags(Kl + wave*4096, m16, q, Kf);
    } else {
#pragma unroll
      for(int ks = 0; ks < 2; ks++)
#pragma unroll
        for(int t = 0; t < 4; t++){
          short8 v;
#pragma unroll
          for(int j = 0; j < 8; j++) v[j] = (short)Kl[wave*4096 + swz(ks*32 + q*8 + j, t*16 + m16)];
          Kf[ks][t] = v;
        }
    }
    const int row = tid >> 3, k0 = (tid & 7)*8;
    const int rpos = row*64 + (((tid & 7) ^ (row & 7)) << 3);
    {
      short8 bb;
#pragma unroll
      for(int j = 0; j < 8; j++) bb[j] = (row == k0 + j) ? (short)f2bf(1.f/64.f) : (short)0;
      *(short8*)(rhoZ + rpos) = bb;
    }
    __syncthreads();
    const float S13 = 1.f/8192.f;        // fixed per-iter scale (lambda ~ 2^13)
#pragma unroll
    for(int it = 0; it < POWER_ITERS; it++){
      // stage 1: C = rho * Kdir^T (rho symmetric)
      short8 Ar[2][4];
#pragma unroll
      for(int ks = 0; ks < 2; ks++)
#pragma unroll
        for(int t = 0; t < 4; t++) Ar[ks][t] = lds_frag(rhoZ, t*16 + m16, ks*32 + q*8);
      f32x4 C[4][4];
#pragma unroll
      for(int i = 0; i < 4; i++)
#pragma unroll
        for(int j = 0; j < 4; j++) C[i][j] = f32x4{0.f,0.f,0.f,0.f};
#pragma unroll
      for(int ks = 0; ks < 2; ks++)
#pragma unroll
        for(int i = 0; i < 4; i++)
#pragma unroll
          for(int j = 0; j < 4; j++)
            C[i][j] = mfma_bf16(Ar[ks][i], Kf[ks][j], C[i][j]);
      write_CT_lds(zw, lane, C);
      // stage 2: C = Kdir * (..)^T
      short8 Bt[2][4];
#pragma unroll
      for(int ks = 0; ks < 2; ks++)
#pragma unroll
        for(int t = 0; t < 4; t++) Bt[ks][t] = lds_frag(zw, t*16 + m16, ks*32 + q*8);
#pragma unroll
      for(int i = 0; i < 4; i++)
#pragma unroll
        for(int j = 0; j < 4; j++) C[i][j] = f32x4{0.f,0.f,0.f,0.f};
#pragma unroll
      for(int ks = 0; ks < 2; ks++)
#pragma unroll
        for(int i = 0; i < 4; i++)
#pragma unroll
          for(int j = 0; j < 4; j++)
            C[i][j] = mfma_bf16(Kf[ks][i], Bt[ks][j], C[i][j]);
      write_CT_lds(zw, lane, C);
      __syncthreads();
      float v[8];
#pragma unroll
      for(int j2 = 0; j2 < 8; j2++) v[j2] = 0.f;
#pragma unroll
      for(int z = 0; z < 8; z++){
        short8 f = lds_frag(zones + z*4096, row, k0);
#pragma unroll
        for(int j2 = 0; j2 < 8; j2++) v[j2] += bf2f((u16)f[j2]);
      }
      if(it != POWER_ITERS - 1){
        u32x4 u = { pack2bf(v[0]*S13, v[1]*S13), pack2bf(v[2]*S13, v[3]*S13),
                    pack2bf(v[4]*S13, v[5]*S13), pack2bf(v[6]*S13, v[7]*S13) };
        *(short8*)(rhoZ + rpos) = __builtin_bit_cast(short8, u);
        __syncthreads();
      } else {
        float pd = (k0 <= row && row < k0 + 8) ? v[row - k0] : 0.f;
        for(int off = 32; off; off >>= 1) pd += __shfl_xor(pd, off, 64);
        if(lane == 0) redf[wave] = pd;
        __syncthreads();
        float tr = 0.f;
#pragma unroll
        for(int w = 0; w < 8; w++) tr += redf[w];
        float inv = 1.f/tr;
        float* ro = left ? rhoL : rhoR;
#pragma unroll
        for(int j2 = 0; j2 < 8; j2++) ro[row*64 + k0 + j2] = v[j2]*inv;
        u32x4 u = { pack2bf(v[0]*inv, v[1]*inv), pack2bf(v[2]*inv, v[3]*inv),
                    pack2bf(v[4]*inv, v[5]*inv), pack2bf(v[6]*inv, v[7]*inv) };
        *(short8*)(rhoZ + rpos) = __builtin_bit_cast(short8, u);   // normalized bf16 stays in LDS
        __syncthreads();
      }
    }
    if(left){
      // lambda = tr(rho_l * sum_a K_a K_a^T); wave a handles K_a
      short8 Ka[2][4];
      ld_zn_frags(Kl + wave*4096, m16, q, Ka);
      f32x4 G[4][4];
#pragma unroll
      for(int i = 0; i < 4; i++)
#pragma unroll
        for(int j = 0; j < 4; j++) G[i][j] = f32x4{0.f,0.f,0.f,0.f};
#pragma unroll
      for(int ks = 0; ks < 2; ks++)
#pragma unroll
        for(int i = 0; i < 4; i++)
#pragma unroll
          for(int j = 0; j < 4; j++)
            G[i][j] = mfma_bf16(Ka[ks][i], Ka[ks][j], G[i][j]);
      float lp = 0.f;
#pragma unroll
      for(int i = 0; i < 4; i++)
#pragma unroll
        for(int j = 0; j < 4; j++)
#pragma unroll
          for(int t = 0; t < 4; t++){
            int r = i*16 + q*4 + t, c = j*16 + m16;
            lp += G[i][j][t] * bf2f(rhoZ[swz(r, c)]);
          }
      for(int off = 32; off; off >>= 1) lp += __shfl_xor(lp, off, 64);
      if(lane == 0) redf[wave] = lp;
      __syncthreads();
      if(tid == 0){
        float m = 0.f;
#pragma unroll
        for(int w = 0; w < 8; w++) m += redf[w];
        muv[0] = m;
      }
    }
    __syncthreads();
  }

  // ================= PHASE A (all 256 blocks): node b = 64 seq-mats =================
  {
    int s0 = __shfl(sv, 0, 64);
    lds_transpose(Kl + s0*4096, zw, lane);
    f32x4 C[4][4];
    short8 Af[2][4];
#pragma unroll 1
    for(int j = 1; j < 8; j++){
      int sj = __shfl(sv, j, 64);
      ld_zn_frags(Kl + sj*4096, m16, q, Af);
      chain_step_A(Af, zw, lane, C, j < 7);
    }
    { float s; int e = norm_es(C, s);
      if(!(wave & 1)) write_CT_lds_s(zw, lane, C, s);   // even wave -> Zt
      else            scatter_C_rm(zw, lane, C, s);     // odd wave  -> Zn
      if(lane == 0) exps[wave] = e; }
    __syncthreads();
    if(wave < 4){                                  // combine L1
      short8 Aa[2][4]; f32x4 Y[4][4];
      ld_zn_frags(zones + (2*wave + 1)*4096, m16, q, Aa);
      bool e2 = !(wave & 1);
      chain_step_A(Aa, zones + 2*wave*4096, lane, Y, e2);
      if(!e2) scatter_C_rm(zones + 2*wave*4096, lane, Y, 1.f);
    }
    __syncthreads();
    if(wave < 2){                                  // combine L2
      short8 Aa[2][4]; f32x4 Y[4][4];
      ld_zn_frags(zones + (4*wave + 2)*4096, m16, q, Aa);
      chain_step_A(Aa, zones + 4*wave*4096, lane, Y, wave == 0);
      if(wave == 1) scatter_C_rm(zones + 4*4096, lane, Y, 1.f);
    }
    __syncthreads();
    if(wave == 0){                                 // combine L3 + norm
      short8 Aa[2][4]; f32x4 M[4][4];
      ld_zn_frags(zones + 4*4096, m16, q, Aa);
      chain_step_A(Aa, zones, lane, M, false);
      float sr; int er = norm_es(M, sr);
      scatter_C_rm(zones, lane, M, sr);
      if(lane == 0){
        int ss = er;
#pragma unroll
        for(int w = 0; w < 8; w++) ss += exps[w];
        Sarr[b] = ss;
      }
    }
    __syncthreads();
    { int row = tid >> 3, c0 = (tid & 7)*8;
      *(short8*)(Nbuf + (size_t)b*4096 + row*64 + c0) = lds_frag(zones, row, c0); }
  }
  arrive(bar);                                     // c1
  if(b == 1) arrive(bar + 1);                      // c2 (lambda+rhoL published)

  if(b >= 2 && b < 18){
    // ================= COMBINE: 16 Nbuf nodes -> one M2 node =================
    wait_ge(bar, 256);
    const int idx = b - 2, nb = idx*16;
    short8 Af[2][4];
    f32x4 C[4][4];
    ld_bf16_frags(Nbuf + (size_t)(nb + 2*wave + 1)*4096, m16, q, Af);
    load_Pt_transpose(Nbuf + (size_t)(nb + 2*wave)*4096, zw, lane);
    chain_step_A(Af, zw, lane, C, false);
    { float s; int e = norm_es(C, s);
      if(!(wave & 1)) write_CT_lds_s(zw, lane, C, s);
      else            scatter_C_rm(zw, lane, C, s);
      if(lane == 0) exps[wave] = e; }
    __syncthreads();
    if(wave < 4){
      short8 Aa[2][4]; f32x4 Y[4][4];
      ld_zn_frags(zones + (2*wave + 1)*4096, m16, q, Aa);
      bool e2 = !(wave & 1);
      chain_step_A(Aa, zones + 2*wave*4096, lane, Y, e2);
      if(!e2) scatter_C_rm(zones + 2*wave*4096, lane, Y, 1.f);
    }
    __syncthreads();
    if(wave < 2){
      short8 Aa[2][4]; f32x4 Y[4][4];
      ld_zn_frags(zones + (4*wave + 2)*4096, m16, q, Aa);
      chain_step_A(Aa, zones + 4*wave*4096, lane, Y, wave == 0);
      if(wave == 1) scatter_C_rm(zones + 4*4096, lane, Y, 1.f);
    }
    __syncthreads();
    if(wave == 0){
      short8 Aa[2][4]; f32x4 M[4][4];
      ld_zn_frags(zones + 4*4096, m16, q, Aa);
      chain_step_A(Aa, zones, lane, M, false);
      float sr; int er = norm_es(M, sr);
      scatter_C_rm(zones, lane, M, sr);
      if(lane == 0){
        int ss = er;
#pragma unroll
        for(int w = 0; w < 8; w++) ss += exps[w];
        Earr[idx] = ss;
      }
    }
    __syncthreads();
    { int row = tid >> 3, c0 = (tid & 7)*8;
      *(short8*)(M2buf + (size_t)idx*4096 + row*64 + c0) = lds_frag(zones, row, c0); }
    arrive(bar + 1);                               // c2
  }

  if(b == 0){
    // ================= FINAL =================
    wait_ge(bar + 1, 17);
    // pair round: wave w: X_w = M2[2w+1]*M2[2w]
    short8 Af[2][4];
    f32x4 C[4][4];
    ld_bf16_frags(M2buf + (size_t)(2*wave + 1)*4096, m16, q, Af);
    load_Pt_transpose(M2buf + (size_t)(2*wave)*4096, zw, lane);
    chain_step_A(Af, zw, lane, C, false);
    { float s; int e = norm_es(C, s);
      if(!(wave & 1)) write_CT_lds_s(zw, lane, C, s);
      else            scatter_C_rm(zw, lane, C, s);
      if(lane == 0) exps[wave] = e; }
    __syncthreads();
    // L1 (waves 0-3) + side jobs (waves 4,5)
    if(wave < 4){
      short8 Aa[2][4]; f32x4 Y[4][4];
      ld_zn_frags(zones + (2*wave + 1)*4096, m16, q, Aa);
      bool e2 = !(wave & 1);
      chain_step_A(Aa, zones + 2*wave*4096, lane, Y, e2);
      if(!e2) scatter_C_rm(zones + 2*wave*4096, lane, Y, 1.f);
    } else if(wave == 4){
      float t2 = 0.f;
      for(int j = 0; j < 64; j++){
        int idx = lane + 64*j;
        t2 += rhoR[idx] * rhoL[idx];
      }
      for(int off = 32; off; off >>= 1) t2 += __shfl_xor(t2, off, 64);
      if(lane == 0) sh_t2 = t2;
    } else if(wave == 5){
      int s = Sarr[lane] + Sarr[lane + 64] + Sarr[lane + 128] + Sarr[lane + 192];
      if(lane < 16) s += Earr[lane];
      for(int off = 32; off; off >>= 1) s += __shfl_xor(s, off, 64);
      if(lane == 0) sh_S = s;
    }
    __syncthreads();
    // L2 (waves 0,1); wave2: rho_l -> zone3 (free after L1)
    if(wave < 2){
      short8 Aa[2][4]; f32x4 Y[4][4];
      ld_zn_frags(zones + (4*wave + 2)*4096, m16, q, Aa);
      chain_step_A(Aa, zones + 4*wave*4096, lane, Y, wave == 0);
      if(wave == 1) scatter_C_rm(zones + 4*4096, lane, Y, 1.f);
    } else if(wave == 2){
#pragma unroll
      for(int g = 0; g < 8; g++){
        const float* p = rhoL + lane*64 + g*8;
        float4 a = *(const float4*)p, c = *(const float4*)(p + 4);
        u32x4 u = { pack2bf(a.x,a.y), pack2bf(a.z,a.w), pack2bf(c.x,c.y), pack2bf(c.z,c.w) };
        *(short8*)(zones + 3*4096 + lane*64 + ((g ^ (lane & 7)) << 3)) = __builtin_bit_cast(short8, u);
      }
    }
    __syncthreads();
    // L3 + contraction (wave 0)
    if(wave == 0){
      short8 Aa[2][4];
      ld_zn_frags(zones + 4*4096, m16, q, Aa);
      chain_step_A(Aa, zones, lane, C, false);
      float sM; int eM = norm_es(C, sM);
      u16* Pm = zones + 1*4096;                    // free zone
      scatter_C_rm(Pm, lane, C, sM);               // M (Zn)

      // U = M * rho_r  (rho_r bf16 in rhoZ, symmetric) -> U^T in zone2
      short8 Ua[2][4], Ub[2][4];
      ld_zn_frags(Pm, m16, q, Ua);
      ld_zn_frags(rhoZ, m16, q, Ub);
#pragma unroll
      for(int i = 0; i < 4; i++)
#pragma unroll
        for(int j = 0; j < 4; j++) C[i][j] = f32x4{0.f,0.f,0.f,0.f};
#pragma unroll
      for(int ks = 0; ks < 2; ks++)
#pragma unroll
        for(int i = 0; i < 4; i++)
#pragma unroll
          for(int j = 0; j < 4; j++)
            C[i][j] = mfma_bf16(Ua[ks][i], Ub[ks][j], C[i][j]);
      write_CT_lds(zones + 2*4096, lane, C);

      // D2 = rho_l * U
      ld_zn_frags(zones + 3*4096, m16, q, Ua);
#pragma unroll
      for(int ks = 0; ks < 2; ks++)
#pragma unroll
        for(int t = 0; t < 4; t++) Ub[ks][t] = lds_frag(zones + 2*4096, t*16 + m16, ks*32 + q*8);
#pragma unroll
      for(int i = 0; i < 4; i++)
#pragma unroll
        for(int j = 0; j < 4; j++) C[i][j] = f32x4{0.f,0.f,0.f,0.f};
#pragma unroll
      for(int ks = 0; ks < 2; ks++)
#pragma unroll
        for(int i = 0; i < 4; i++)
#pragma unroll
          for(int j = 0; j < 4; j++)
            C[i][j] = mfma_bf16(Ua[ks][i], Ub[ks][j], C[i][j]);

      // t1 = sum_ij D2_ij * M_ij
      float part = 0.f;
#pragma unroll
      for(int i = 0; i < 4; i++)
#pragma unroll
        for(int j = 0; j < 4; j++)
#pragma unroll
          for(int t = 0; t < 4; t++){
            int r = i*16 + q*4 + t, c = j*16 + m16;
            part += C[i][j][t] * bf2f(Pm[swz(r, c)]);
          }
      for(int off = 32; off; off >>= 1) part += __shfl_xor(part, off, 64);
      if(lane == 0){
        double t1  = (double)part;
        double lam = (double)muv[0];
        double S   = (double)sh_S + eM;
#pragma unroll
        for(int w = 0; w < 8; w++) S += exps[w];
        double logp = 16384.0*log2(lam) - 2.0*S - log2(t1) + log2((double)sh_t2);
        outp[0] = (float)logp;
      }
    }
  }
}

// ---------- launch ----------
extern "C" void kernel_launch(void* const* d_in, const int* in_sizes, int n_in,
                              void* d_out, int out_size, void* d_ws, size_t ws_size,
                              hipStream_t stream) {
  const float* K  = (const float*)d_in[0];   // (8,64,64) fp32
  const int* seq  = (const int*)d_in[1];     // (16384,) int32
  char* ws = (char*)d_ws;
  u16*   Nbuf  = (u16*)(ws);                   // 256 * 8KB = 2 MB
  u16*   M2buf = (u16*)(ws + 2097152);         // 16 * 8KB = 128 KB
  int*   Sarr  = (int*)(ws + 2228224);         // 256 ints
  int*   Earr  = (int*)(ws + 2229248);         // 16 ints
  float* rhoR  = (float*)(ws + 2229760);       // 16 KB
  float* rhoL  = (float*)(ws + 2246144);       // 16 KB
  float* muv   = (float*)(ws + 2262528);       // 1 float
  int*   bar   = (int*)(ws + 2262592);         // 2 ints (c1, c2)

  hipMemsetAsync(bar, 0, 8, stream);
  kall<<<256, 512, 0, stream>>>(K, seq, Nbuf, M2buf, Sarr, Earr, rhoR, rhoL, muv, bar,
                                (float*)d_out);
}

// Round 11
// 109.312 us; speedup vs baseline: 1.5695x; 1.0110x over previous
//
#include <hip/hip_runtime.h>

typedef unsigned short u16;
typedef unsigned int   u32;
typedef short  short8  __attribute__((ext_vector_type(8)));
typedef __bf16 bf16x8  __attribute__((ext_vector_type(8)));
typedef float  f32x4   __attribute__((ext_vector_type(4)));
typedef u32    u32x4   __attribute__((ext_vector_type(4)));

#define POWER_ITERS 3

// ---------- helpers ----------
__device__ __forceinline__ u16 f2bf(float f){ return __builtin_bit_cast(u16, (__bf16)f); }
__device__ __forceinline__ u32 pack2bf(float a, float b){
  return (u32)__builtin_bit_cast(u16, (__bf16)a) | ((u32)__builtin_bit_cast(u16, (__bf16)b) << 16);
}
__device__ __forceinline__ float bf2f(u16 h){ return __uint_as_float(((u32)h) << 16); }

__device__ __forceinline__ f32x4 mfma_bf16(short8 a, short8 b, f32x4 c){
  return __builtin_amdgcn_mfma_f32_16x16x32_bf16(
      __builtin_bit_cast(bf16x8, a), __builtin_bit_cast(bf16x8, b), c, 0, 0, 0);
}

// swizzled LDS address (u16 units) of element [row][k] of a 64x64 matrix
__device__ __forceinline__ int swz(int row, int k){
  return row*64 + ((((k >> 3) ^ (row & 7)) << 3) | (k & 7));
}
__device__ __forceinline__ short8 lds_frag(const u16* P, int row, int k0){
  int pos = (k0 >> 3) ^ (row & 7);
  return *(const short8*)(P + row*64 + pos*8);
}
__device__ __forceinline__ short8 g_frag(const u16* __restrict__ M, int row, int k0){
  return *(const short8*)(M + row*64 + k0);
}

// write C/D regs (matrix X) as X^T into swizzled LDS (Zt), scaled
__device__ __forceinline__ void write_CT_lds_s(u16* Pt, int lane, const f32x4 (&C)[4][4], float s){
  const int m16 = lane & 15, q = lane >> 4;
#pragma unroll
  for(int i = 0; i < 4; i++){
    const int r0 = i*16 + q*4;
#pragma unroll
    for(int j = 0; j < 4; j++){
      const int c = j*16 + m16;
      const int addr = c*64 + ((((r0 >> 3) ^ (c & 7)) << 3) | (r0 & 7));
      u32 lo = pack2bf(C[i][j][0]*s, C[i][j][1]*s);
      u32 hi = pack2bf(C[i][j][2]*s, C[i][j][3]*s);
      *(uint2*)(Pt + addr) = make_uint2(lo, hi);
    }
  }
}
__device__ __forceinline__ void write_CT_lds(u16* Pt, int lane, const f32x4 (&C)[4][4]){
  write_CT_lds_s(Pt, lane, C, 1.f);
}

// write C ROW-MAJOR swizzled (Zn), scaled — scalar scatter
__device__ __forceinline__ void scatter_C_rm(u16* Z, int lane, const f32x4 (&C)[4][4], float s){
  const int m16 = lane & 15, q = lane >> 4;
#pragma unroll
  for(int i = 0; i < 4; i++)
#pragma unroll
    for(int j = 0; j < 4; j++)
#pragma unroll
      for(int t = 0; t < 4; t++)
        Z[swz(i*16 + q*4 + t, j*16 + m16)] = f2bf(C[i][j][t]*s);
}

// C = A (regs) * P (Pt = Zt of P); optional writeback of C^T into Pt
__device__ __forceinline__ void chain_step_A(const short8 (&Af)[2][4], u16* Pt, int lane,
                                             f32x4 (&C)[4][4], bool wb){
  const int m16 = lane & 15, q = lane >> 4;
  short8 Bf[2][4];
#pragma unroll
  for(int ks = 0; ks < 2; ks++)
#pragma unroll
    for(int t = 0; t < 4; t++) Bf[ks][t] = lds_frag(Pt, t*16 + m16, ks*32 + q*8);
#pragma unroll
  for(int i = 0; i < 4; i++)
#pragma unroll
    for(int j = 0; j < 4; j++) C[i][j] = f32x4{0.f,0.f,0.f,0.f};
#pragma unroll
  for(int ks = 0; ks < 2; ks++)
#pragma unroll
    for(int i = 0; i < 4; i++)
#pragma unroll
      for(int j = 0; j < 4; j++)
        C[i][j] = mfma_bf16(Af[ks][i], Bf[ks][j], C[i][j]);
  if(wb) write_CT_lds(Pt, lane, C);
}

__device__ __forceinline__ void ld_zn_frags(const u16* Zn, int m16, int q, short8 (&Af)[2][4]){
#pragma unroll
  for(int ks = 0; ks < 2; ks++)
#pragma unroll
    for(int t = 0; t < 4; t++) Af[ks][t] = lds_frag(Zn, t*16 + m16, ks*32 + q*8);
}
__device__ __forceinline__ void ld_bf16_frags(const u16* __restrict__ M, int m16, int q, short8 (&Af)[2][4]){
#pragma unroll
  for(int ks = 0; ks < 2; ks++)
#pragma unroll
    for(int t = 0; t < 4; t++) Af[ks][t] = g_frag(M, t*16 + m16, ks*32 + q*8);
}

// P = N (global row-major bf16) -> Zt of P
__device__ __forceinline__ void load_Pt_transpose(const u16* __restrict__ N, u16* Pt, int lane){
#pragma unroll
  for(int g = 0; g < 8; g++){
    short8 v = *(const short8*)(N + lane*64 + g*8);
#pragma unroll
    for(int t = 0; t < 8; t++) Pt[swz(g*8 + t, lane)] = (u16)v[t];
  }
}
// Pt <- Zt of an LDS Zn zone
__device__ __forceinline__ void lds_transpose(const u16* Z, u16* Pt, int lane){
#pragma unroll
  for(int g = 0; g < 8; g++){
    short8 f = lds_frag(Z, lane, g*8);
#pragma unroll
    for(int j = 0; j < 8; j++) Pt[swz(g*8 + j, lane)] = (u16)f[j];
  }
}

__device__ __forceinline__ float wave_max(float mx){
  for(int off = 32; off; off >>= 1) mx = fmaxf(mx, __shfl_xor(mx, off, 64));
  return mx;
}
__device__ __forceinline__ int norm_es(const f32x4 (&C)[4][4], float& s){
  float mx = 0.f;
#pragma unroll
  for(int i = 0; i < 4; i++)
#pragma unroll
    for(int j = 0; j < 4; j++)
#pragma unroll
      for(int t = 0; t < 4; t++) mx = fmaxf(mx, C[i][j][t]);   // entries all positive
  mx = wave_max(mx);
  int e; (void)frexpf(mx, &e);
  s = ldexpf(1.f, -e);
  return e;
}

// ---------- coherent partial barriers, SHARDED counters (one per 64B line) ----------
// arrival contention was the R8/R10 stall: 256 atomic RMWs + 254 pollers on ONE line.
__device__ __forceinline__ void arrive(int* c){
  __syncthreads();
  if(threadIdx.x == 0){
    __threadfence();
    __hip_atomic_fetch_add(c, 1, __ATOMIC_RELEASE, __HIP_MEMORY_SCOPE_AGENT);
  }
}
__device__ __forceinline__ void wait_ge(int* c, int target){
  if(threadIdx.x == 0){
    while(__hip_atomic_load(c, __ATOMIC_ACQUIRE, __HIP_MEMORY_SCOPE_AGENT) < target)
      __builtin_amdgcn_s_sleep(2);
    __threadfence();
  }
  __syncthreads();
}

// ==================== single kernel: 256 blocks x 512 threads, 1 block/CU ====================
// ALL blocks: stage K->LDS, then phase A (node b: 64 seq-mats) -> Nbuf[b], arrive c1[b>>4]
//   (c1 = 16 counters, one 64B line each -> 16 arrivals/line, no global rendezvous).
// blocks 2..17: wait c1[b-2]>=16 (their OWN 16 producers), combine 16 nodes -> M2buf, arrive c2.
// blocks 0,1: power iteration AFTER phase A (parallel with combines); b1: +lambda, arrive c2.
// block 0: wait c2>=17, final 16->1 combine + contraction -> out.
__global__ __launch_bounds__(512) void kall(const float* __restrict__ K, const int* __restrict__ seq,
                                            u16* __restrict__ Nbuf, u16* __restrict__ M2buf,
                                            int* __restrict__ Sarr, int* __restrict__ Earr,
                                            float* __restrict__ rhoR, float* __restrict__ rhoL,
                                            float* __restrict__ muv, int* __restrict__ bar,
                                            float* __restrict__ outp){
  __shared__ __align__(16) u16 Kl[8*4096];     // bf16 K (Zn swizzled)
  __shared__ __align__(16) u16 zones[8*4096];
  __shared__ __align__(16) u16 rhoZ[4096];
  __shared__ float redf[8];
  __shared__ int exps[8];
  __shared__ float sh_t2;
  __shared__ int sh_S;
  const int tid = threadIdx.x, lane = tid & 63, wave = tid >> 6, b = blockIdx.x;
  const int m16 = lane & 15, q = lane >> 4;
  u16* zw = zones + wave*4096;

  // stage K[wave] fp32 -> Kl (Zn swizzled); lane owns row = lane
#pragma unroll
  for(int g = 0; g < 8; g++){
    const float* p = K + (size_t)wave*4096 + lane*64 + g*8;
    float4 a = *(const float4*)p, c = *(const float4*)(p + 4);
    u32x4 u = { pack2bf(a.x,a.y), pack2bf(a.z,a.w), pack2bf(c.x,c.y), pack2bf(c.z,c.w) };
    *(short8*)(Kl + wave*4096 + lane*64 + ((g ^ (lane & 7)) << 3)) = __builtin_bit_cast(short8, u);
  }
  int sv = (lane < 8) ? seq[b*64 + wave*8 + lane] : 0;
  __syncthreads();

  // ================= PHASE A (all 256 blocks): node b = 64 seq-mats =================
  {
    int s0 = __shfl(sv, 0, 64);
    lds_transpose(Kl + s0*4096, zw, lane);
    f32x4 C[4][4];
    short8 Af[2][4];
#pragma unroll 1
    for(int j = 1; j < 8; j++){
      int sj = __shfl(sv, j, 64);
      ld_zn_frags(Kl + sj*4096, m16, q, Af);
      chain_step_A(Af, zw, lane, C, j < 7);
    }
    { float s; int e = norm_es(C, s);
      if(!(wave & 1)) write_CT_lds_s(zw, lane, C, s);   // even wave -> Zt
      else            scatter_C_rm(zw, lane, C, s);     // odd wave  -> Zn
      if(lane == 0) exps[wave] = e; }
    __syncthreads();
    if(wave < 4){                                  // combine L1
      short8 Aa[2][4]; f32x4 Y[4][4];
      ld_zn_frags(zones + (2*wave + 1)*4096, m16, q, Aa);
      bool e2 = !(wave & 1);
      chain_step_A(Aa, zones + 2*wave*4096, lane, Y, e2);
      if(!e2) scatter_C_rm(zones + 2*wave*4096, lane, Y, 1.f);
    }
    __syncthreads();
    if(wave < 2){                                  // combine L2
      short8 Aa[2][4]; f32x4 Y[4][4];
      ld_zn_frags(zones + (4*wave + 2)*4096, m16, q, Aa);
      chain_step_A(Aa, zones + 4*wave*4096, lane, Y, wave == 0);
      if(wave == 1) scatter_C_rm(zones + 4*4096, lane, Y, 1.f);
    }
    __syncthreads();
    if(wave == 0){                                 // combine L3 + norm
      short8 Aa[2][4]; f32x4 M[4][4];
      ld_zn_frags(zones + 4*4096, m16, q, Aa);
      chain_step_A(Aa, zones, lane, M, false);
      float sr; int er = norm_es(M, sr);
      scatter_C_rm(zones, lane, M, sr);
      if(lane == 0){
        int ss = er;
#pragma unroll
        for(int w = 0; w < 8; w++) ss += exps[w];
        Sarr[b] = ss;
      }
    }
    __syncthreads();
    { int row = tid >> 3, c0 = (tid & 7)*8;
      *(short8*)(Nbuf + (size_t)b*4096 + row*64 + c0) = lds_frag(zones, row, c0); }
  }
  arrive(bar + (b >> 4)*16);                       // c1[group], sharded

  if(b < 2){
    // ================= POWER (after phase A; parallel with combines) =================
    const bool left = (b == 1);
    short8 Kf[2][4];
    if(!left){
      ld_zn_frags(Kl + wave*4096, m16, q, Kf);
    } else {
#pragma unroll
      for(int ks = 0; ks < 2; ks++)
#pragma unroll
        for(int t = 0; t < 4; t++){
          short8 v;
#pragma unroll
          for(int j = 0; j < 8; j++) v[j] = (short)Kl[wave*4096 + swz(ks*32 + q*8 + j, t*16 + m16)];
          Kf[ks][t] = v;
        }
    }
    const int row = tid >> 3, k0 = (tid & 7)*8;
    const int rpos = row*64 + (((tid & 7) ^ (row & 7)) << 3);
    {
      short8 bb;
#pragma unroll
      for(int j = 0; j < 8; j++) bb[j] = (row == k0 + j) ? (short)f2bf(1.f/64.f) : (short)0;
      *(short8*)(rhoZ + rpos) = bb;
    }
    __syncthreads();
    const float S13 = 1.f/8192.f;        // fixed per-iter scale (lambda ~ 2^13)
#pragma unroll
    for(int it = 0; it < POWER_ITERS; it++){
      short8 Ar[2][4];
#pragma unroll
      for(int ks = 0; ks < 2; ks++)
#pragma unroll
        for(int t = 0; t < 4; t++) Ar[ks][t] = lds_frag(rhoZ, t*16 + m16, ks*32 + q*8);
      f32x4 C[4][4];
#pragma unroll
      for(int i = 0; i < 4; i++)
#pragma unroll
        for(int j = 0; j < 4; j++) C[i][j] = f32x4{0.f,0.f,0.f,0.f};
#pragma unroll
      for(int ks = 0; ks < 2; ks++)
#pragma unroll
        for(int i = 0; i < 4; i++)
#pragma unroll
          for(int j = 0; j < 4; j++)
            C[i][j] = mfma_bf16(Ar[ks][i], Kf[ks][j], C[i][j]);   // rho * Kdir^T
      write_CT_lds(zw, lane, C);
      short8 Bt[2][4];
#pragma unroll
      for(int ks = 0; ks < 2; ks++)
#pragma unroll
        for(int t = 0; t < 4; t++) Bt[ks][t] = lds_frag(zw, t*16 + m16, ks*32 + q*8);
#pragma unroll
      for(int i = 0; i < 4; i++)
#pragma unroll
        for(int j = 0; j < 4; j++) C[i][j] = f32x4{0.f,0.f,0.f,0.f};
#pragma unroll
      for(int ks = 0; ks < 2; ks++)
#pragma unroll
        for(int i = 0; i < 4; i++)
#pragma unroll
          for(int j = 0; j < 4; j++)
            C[i][j] = mfma_bf16(Kf[ks][i], Bt[ks][j], C[i][j]);   // Kdir * (..)^T
      write_CT_lds(zw, lane, C);
      __syncthreads();
      float v[8];
#pragma unroll
      for(int j2 = 0; j2 < 8; j2++) v[j2] = 0.f;
#pragma unroll
      for(int z = 0; z < 8; z++){
        short8 f = lds_frag(zones + z*4096, row, k0);
#pragma unroll
        for(int j2 = 0; j2 < 8; j2++) v[j2] += bf2f((u16)f[j2]);
      }
      if(it != POWER_ITERS - 1){
        u32x4 u = { pack2bf(v[0]*S13, v[1]*S13), pack2bf(v[2]*S13, v[3]*S13),
                    pack2bf(v[4]*S13, v[5]*S13), pack2bf(v[6]*S13, v[7]*S13) };
        *(short8*)(rhoZ + rpos) = __builtin_bit_cast(short8, u);
        __syncthreads();
      } else {
        float pd = (k0 <= row && row < k0 + 8) ? v[row - k0] : 0.f;
        for(int off = 32; off; off >>= 1) pd += __shfl_xor(pd, off, 64);
        if(lane == 0) redf[wave] = pd;
        __syncthreads();
        float tr = 0.f;
#pragma unroll
        for(int w = 0; w < 8; w++) tr += redf[w];
        float inv = 1.f/tr;
        float* ro = left ? rhoL : rhoR;
#pragma unroll
        for(int j2 = 0; j2 < 8; j2++) ro[row*64 + k0 + j2] = v[j2]*inv;
        u32x4 u = { pack2bf(v[0]*inv, v[1]*inv), pack2bf(v[2]*inv, v[3]*inv),
                    pack2bf(v[4]*inv, v[5]*inv), pack2bf(v[6]*inv, v[7]*inv) };
        *(short8*)(rhoZ + rpos) = __builtin_bit_cast(short8, u);   // normalized bf16 stays in LDS
        __syncthreads();
      }
    }
    if(left){
      // lambda = tr(rho_l * sum_a K_a K_a^T); wave a handles K_a
      short8 Ka[2][4];
      ld_zn_frags(Kl + wave*4096, m16, q, Ka);
      f32x4 G[4][4];
#pragma unroll
      for(int i = 0; i < 4; i++)
#pragma unroll
        for(int j = 0; j < 4; j++) G[i][j] = f32x4{0.f,0.f,0.f,0.f};
#pragma unroll
      for(int ks = 0; ks < 2; ks++)
#pragma unroll
        for(int i = 0; i < 4; i++)
#pragma unroll
          for(int j = 0; j < 4; j++)
            G[i][j] = mfma_bf16(Ka[ks][i], Ka[ks][j], G[i][j]);
      float lp = 0.f;
#pragma unroll
      for(int i = 0; i < 4; i++)
#pragma unroll
        for(int j = 0; j < 4; j++)
#pragma unroll
          for(int t = 0; t < 4; t++){
            int r = i*16 + q*4 + t, c = j*16 + m16;
            lp += G[i][j][t] * bf2f(rhoZ[swz(r, c)]);
          }
      for(int off = 32; off; off >>= 1) lp += __shfl_xor(lp, off, 64);
      if(lane == 0) redf[wave] = lp;
      __syncthreads();
      if(tid == 0){
        float m = 0.f;
#pragma unroll
        for(int w = 0; w < 8; w++) m += redf[w];
        muv[0] = m;
      }
      arrive(bar + 256);                           // c2 (lambda + rhoL published)
    }
  }

  if(b >= 2 && b < 18){
    // ================= COMBINE: group (b-2)'s 16 Nbuf nodes -> one M2 node =================
    wait_ge(bar + (b - 2)*16, 16);                 // only OUR 16 producers
    const int idx = b - 2, nb = idx*16;
    short8 Af[2][4];
    f32x4 C[4][4];
    ld_bf16_frags(Nbuf + (size_t)(nb + 2*wave + 1)*4096, m16, q, Af);
    load_Pt_transpose(Nbuf + (size_t)(nb + 2*wave)*4096, zw, lane);
    chain_step_A(Af, zw, lane, C, false);
    { float s; int e = norm_es(C, s);
      if(!(wave & 1)) write_CT_lds_s(zw, lane, C, s);
      else            scatter_C_rm(zw, lane, C, s);
      if(lane == 0) exps[wave] = e; }
    __syncthreads();
    if(wave < 4){
      short8 Aa[2][4]; f32x4 Y[4][4];
      ld_zn_frags(zones + (2*wave + 1)*4096, m16, q, Aa);
      bool e2 = !(wave & 1);
      chain_step_A(Aa, zones + 2*wave*4096, lane, Y, e2);
      if(!e2) scatter_C_rm(zones + 2*wave*4096, lane, Y, 1.f);
    }
    __syncthreads();
    if(wave < 2){
      short8 Aa[2][4]; f32x4 Y[4][4];
      ld_zn_frags(zones + (4*wave + 2)*4096, m16, q, Aa);
      chain_step_A(Aa, zones + 4*wave*4096, lane, Y, wave == 0);
      if(wave == 1) scatter_C_rm(zones + 4*4096, lane, Y, 1.f);
    }
    __syncthreads();
    if(wave == 0){
      short8 Aa[2][4]; f32x4 M[4][4];
      ld_zn_frags(zones + 4*4096, m16, q, Aa);
      chain_step_A(Aa, zones, lane, M, false);
      float sr; int er = norm_es(M, sr);
      scatter_C_rm(zones, lane, M, sr);
      if(lane == 0){
        int ss = er;
#pragma unroll
        for(int w = 0; w < 8; w++) ss += exps[w];
        Earr[idx] = ss;
      }
    }
    __syncthreads();
    { int row = tid >> 3, c0 = (tid & 7)*8;
      *(short8*)(M2buf + (size_t)idx*4096 + row*64 + c0) = lds_frag(zones, row, c0); }
    arrive(bar + 256);                             // c2
  }

  if(b == 0){
    // ================= FINAL =================
    wait_ge(bar + 256, 17);
    // pair round: wave w: X_w = M2[2w+1]*M2[2w]
    short8 Af[2][4];
    f32x4 C[4][4];
    ld_bf16_frags(M2buf + (size_t)(2*wave + 1)*4096, m16, q, Af);
    load_Pt_transpose(M2buf + (size_t)(2*wave)*4096, zw, lane);
    chain_step_A(Af, zw, lane, C, false);
    { float s; int e = norm_es(C, s);
      if(!(wave & 1)) write_CT_lds_s(zw, lane, C, s);
      else            scatter_C_rm(zw, lane, C, s);
      if(lane == 0) exps[wave] = e; }
    __syncthreads();
    // L1 (waves 0-3) + side jobs (waves 4,5)
    if(wave < 4){
      short8 Aa[2][4]; f32x4 Y[4][4];
      ld_zn_frags(zones + (2*wave + 1)*4096, m16, q, Aa);
      bool e2 = !(wave & 1);
      chain_step_A(Aa, zones + 2*wave*4096, lane, Y, e2);
      if(!e2) scatter_C_rm(zones + 2*wave*4096, lane, Y, 1.f);
    } else if(wave == 4){
      float t2 = 0.f;
      for(int j = 0; j < 64; j++){
        int idx = lane + 64*j;
        t2 += rhoR[idx] * rhoL[idx];
      }
      for(int off = 32; off; off >>= 1) t2 += __shfl_xor(t2, off, 64);
      if(lane == 0) sh_t2 = t2;
    } else if(wave == 5){
      int s = Sarr[lane] + Sarr[lane + 64] + Sarr[lane + 128] + Sarr[lane + 192];
      if(lane < 16) s += Earr[lane];
      for(int off = 32; off; off >>= 1) s += __shfl_xor(s, off, 64);
      if(lane == 0) sh_S = s;
    }
    __syncthreads();
    // L2 (waves 0,1); wave2: rho_l -> zone3 (free after L1)
    if(wave < 2){
      short8 Aa[2][4]; f32x4 Y[4][4];
      ld_zn_frags(zones + (4*wave + 2)*4096, m16, q, Aa);
      chain_step_A(Aa, zones + 4*wave*4096, lane, Y, wave == 0);
      if(wave == 1) scatter_C_rm(zones + 4*4096, lane, Y, 1.f);
    } else if(wave == 2){
#pragma unroll
      for(int g = 0; g < 8; g++){
        const float* p = rhoL + lane*64 + g*8;
        float4 a = *(const float4*)p, c = *(const float4*)(p + 4);
        u32x4 u = { pack2bf(a.x,a.y), pack2bf(a.z,a.w), pack2bf(c.x,c.y), pack2bf(c.z,c.w) };
        *(short8*)(zones + 3*4096 + lane*64 + ((g ^ (lane & 7)) << 3)) = __builtin_bit_cast(short8, u);
      }
    }
    __syncthreads();
    // L3 + contraction (wave 0)
    if(wave == 0){
      short8 Aa[2][4];
      ld_zn_frags(zones + 4*4096, m16, q, Aa);
      chain_step_A(Aa, zones, lane, C, false);
      float sM; int eM = norm_es(C, sM);
      u16* Pm = zones + 1*4096;                    // free zone
      scatter_C_rm(Pm, lane, C, sM);               // M (Zn)

      // U = M * rho_r  (rho_r bf16 in rhoZ, symmetric) -> U^T in zone2
      short8 Ua[2][4], Ub[2][4];
      ld_zn_frags(Pm, m16, q, Ua);
      ld_zn_frags(rhoZ, m16, q, Ub);
#pragma unroll
      for(int i = 0; i < 4; i++)
#pragma unroll
        for(int j = 0; j < 4; j++) C[i][j] = f32x4{0.f,0.f,0.f,0.f};
#pragma unroll
      for(int ks = 0; ks < 2; ks++)
#pragma unroll
        for(int i = 0; i < 4; i++)
#pragma unroll
          for(int j = 0; j < 4; j++)
            C[i][j] = mfma_bf16(Ua[ks][i], Ub[ks][j], C[i][j]);
      write_CT_lds(zones + 2*4096, lane, C);

      // D2 = rho_l * U
      ld_zn_frags(zones + 3*4096, m16, q, Ua);
#pragma unroll
      for(int ks = 0; ks < 2; ks++)
#pragma unroll
        for(int t = 0; t < 4; t++) Ub[ks][t] = lds_frag(zones + 2*4096, t*16 + m16, ks*32 + q*8);
#pragma unroll
      for(int i = 0; i < 4; i++)
#pragma unroll
        for(int j = 0; j < 4; j++) C[i][j] = f32x4{0.f,0.f,0.f,0.f};
#pragma unroll
      for(int ks = 0; ks < 2; ks++)
#pragma unroll
        for(int i = 0; i < 4; i++)
#pragma unroll
          for(int j = 0; j < 4; j++)
            C[i][j] = mfma_bf16(Ua[ks][i], Ub[ks][j], C[i][j]);

      // t1 = sum_ij D2_ij * M_ij
      float part = 0.f;
#pragma unroll
      for(int i = 0; i < 4; i++)
#pragma unroll
        for(int j = 0; j < 4; j++)
#pragma unroll
          for(int t = 0; t < 4; t++){
            int r = i*16 + q*4 + t, c = j*16 + m16;
            part += C[i][j][t] * bf2f(Pm[swz(r, c)]);
          }
      for(int off = 32; off; off >>= 1) part += __shfl_xor(part, off, 64);
      if(lane == 0){
        double t1  = (double)part;
        double lam = (double)muv[0];
        double S   = (double)sh_S + eM;
#pragma unroll
        for(int w = 0; w < 8; w++) S += exps[w];
        double logp = 16384.0*log2(lam) - 2.0*S - log2(t1) + log2((double)sh_t2);
        outp[0] = (float)logp;
      }
    }
  }
}

// ---------- launch ----------
extern "C" void kernel_launch(void* const* d_in, const int* in_sizes, int n_in,
                              void* d_out, int out_size, void* d_ws, size_t ws_size,
                              hipStream_t stream) {
  const float* K  = (const float*)d_in[0];   // (8,64,64) fp32
  const int* seq  = (const int*)d_in[1];     // (16384,) int32
  char* ws = (char*)d_ws;
  u16*   Nbuf  = (u16*)(ws);                   // 256 * 8KB = 2 MB
  u16*   M2buf = (u16*)(ws + 2097152);         // 16 * 8KB = 128 KB
  int*   Sarr  = (int*)(ws + 2228224);         // 256 ints
  int*   Earr  = (int*)(ws + 2229248);         // 16 ints
  float* rhoR  = (float*)(ws + 2229760);       // 16 KB
  float* rhoL  = (float*)(ws + 2246144);       // 16 KB
  float* muv   = (float*)(ws + 2262528);       // 1 float
  int*   bar   = (int*)(ws + 2262592);         // c1[16] sharded (16 ints stride, 64B/line) + c2 at [256]

  hipMemsetAsync(bar, 0, (256 + 16)*4, stream);
  kall<<<256, 512, 0, stream>>>(K, seq, Nbuf, M2buf, Sarr, Earr, rhoR, rhoL, muv, bar,
                                (float*)d_out);
}

// Round 12
// 108.175 us; speedup vs baseline: 1.5860x; 1.0105x over previous
//
#include <hip/hip_runtime.h>

typedef unsigned short u16;
typedef unsigned int   u32;
typedef short  short8  __attribute__((ext_vector_type(8)));
typedef __bf16 bf16x8  __attribute__((ext_vector_type(8)));
typedef float  f32x4   __attribute__((ext_vector_type(4)));
typedef u32    u32x4   __attribute__((ext_vector_type(4)));

#define POWER_ITERS 3

// ---------- helpers ----------
__device__ __forceinline__ u16 f2bf(float f){ return __builtin_bit_cast(u16, (__bf16)f); }
__device__ __forceinline__ u32 pack2bf(float a, float b){
  return (u32)__builtin_bit_cast(u16, (__bf16)a) | ((u32)__builtin_bit_cast(u16, (__bf16)b) << 16);
}
__device__ __forceinline__ float bf2f(u16 h){ return __uint_as_float(((u32)h) << 16); }

__device__ __forceinline__ f32x4 mfma_bf16(short8 a, short8 b, f32x4 c){
  return __builtin_amdgcn_mfma_f32_16x16x32_bf16(
      __builtin_bit_cast(bf16x8, a), __builtin_bit_cast(bf16x8, b), c, 0, 0, 0);
}

// swizzled LDS address (u16 units) of element [row][k] of a 64x64 matrix
__device__ __forceinline__ int swz(int row, int k){
  return row*64 + ((((k >> 3) ^ (row & 7)) << 3) | (k & 7));
}
__device__ __forceinline__ short8 lds_frag(const u16* P, int row, int k0){
  int pos = (k0 >> 3) ^ (row & 7);
  return *(const short8*)(P + row*64 + pos*8);
}
__device__ __forceinline__ short8 g_frag(const u16* __restrict__ M, int row, int k0){
  return *(const short8*)(M + row*64 + k0);
}

// write C/D regs (matrix X) as X^T into swizzled LDS (Zt), scaled
__device__ __forceinline__ void write_CT_lds_s(u16* Pt, int lane, const f32x4 (&C)[4][4], float s){
  const int m16 = lane & 15, q = lane >> 4;
#pragma unroll
  for(int i = 0; i < 4; i++){
    const int r0 = i*16 + q*4;
#pragma unroll
    for(int j = 0; j < 4; j++){
      const int c = j*16 + m16;
      const int addr = c*64 + ((((r0 >> 3) ^ (c & 7)) << 3) | (r0 & 7));
      u32 lo = pack2bf(C[i][j][0]*s, C[i][j][1]*s);
      u32 hi = pack2bf(C[i][j][2]*s, C[i][j][3]*s);
      *(uint2*)(Pt + addr) = make_uint2(lo, hi);
    }
  }
}
__device__ __forceinline__ void write_CT_lds(u16* Pt, int lane, const f32x4 (&C)[4][4]){
  write_CT_lds_s(Pt, lane, C, 1.f);
}

// write C ROW-MAJOR swizzled (Zn), scaled — scalar scatter
__device__ __forceinline__ void scatter_C_rm(u16* Z, int lane, const f32x4 (&C)[4][4], float s){
  const int m16 = lane & 15, q = lane >> 4;
#pragma unroll
  for(int i = 0; i < 4; i++)
#pragma unroll
    for(int j = 0; j < 4; j++)
#pragma unroll
      for(int t = 0; t < 4; t++)
        Z[swz(i*16 + q*4 + t, j*16 + m16)] = f2bf(C[i][j][t]*s);
}

// C = A (regs) * P (Pt = Zt of P); optional writeback of C^T into Pt
__device__ __forceinline__ void chain_step_A(const short8 (&Af)[2][4], u16* Pt, int lane,
                                             f32x4 (&C)[4][4], bool wb){
  const int m16 = lane & 15, q = lane >> 4;
  short8 Bf[2][4];
#pragma unroll
  for(int ks = 0; ks < 2; ks++)
#pragma unroll
    for(int t = 0; t < 4; t++) Bf[ks][t] = lds_frag(Pt, t*16 + m16, ks*32 + q*8);
#pragma unroll
  for(int i = 0; i < 4; i++)
#pragma unroll
    for(int j = 0; j < 4; j++) C[i][j] = f32x4{0.f,0.f,0.f,0.f};
#pragma unroll
  for(int ks = 0; ks < 2; ks++)
#pragma unroll
    for(int i = 0; i < 4; i++)
#pragma unroll
      for(int j = 0; j < 4; j++)
        C[i][j] = mfma_bf16(Af[ks][i], Bf[ks][j], C[i][j]);
  if(wb) write_CT_lds(Pt, lane, C);
}

__device__ __forceinline__ void ld_zn_frags(const u16* Zn, int m16, int q, short8 (&Af)[2][4]){
#pragma unroll
  for(int ks = 0; ks < 2; ks++)
#pragma unroll
    for(int t = 0; t < 4; t++) Af[ks][t] = lds_frag(Zn, t*16 + m16, ks*32 + q*8);
}
__device__ __forceinline__ void ld_bf16_frags(const u16* __restrict__ M, int m16, int q, short8 (&Af)[2][4]){
#pragma unroll
  for(int ks = 0; ks < 2; ks++)
#pragma unroll
    for(int t = 0; t < 4; t++) Af[ks][t] = g_frag(M, t*16 + m16, ks*32 + q*8);
}

// P = N (global row-major bf16) -> Zt of P
__device__ __forceinline__ void load_Pt_transpose(const u16* __restrict__ N, u16* Pt, int lane){
#pragma unroll
  for(int g = 0; g < 8; g++){
    short8 v = *(const short8*)(N + lane*64 + g*8);
#pragma unroll
    for(int t = 0; t < 8; t++) Pt[swz(g*8 + t, lane)] = (u16)v[t];
  }
}
// Pt <- Zt of an LDS Zn zone
__device__ __forceinline__ void lds_transpose(const u16* Z, u16* Pt, int lane){
#pragma unroll
  for(int g = 0; g < 8; g++){
    short8 f = lds_frag(Z, lane, g*8);
#pragma unroll
    for(int j = 0; j < 8; j++) Pt[swz(g*8 + j, lane)] = (u16)f[j];
  }
}

__device__ __forceinline__ float wave_max(float mx){
  for(int off = 32; off; off >>= 1) mx = fmaxf(mx, __shfl_xor(mx, off, 64));
  return mx;
}
__device__ __forceinline__ int norm_es(const f32x4 (&C)[4][4], float& s){
  float mx = 0.f;
#pragma unroll
  for(int i = 0; i < 4; i++)
#pragma unroll
    for(int j = 0; j < 4; j++)
#pragma unroll
      for(int t = 0; t < 4; t++) mx = fmaxf(mx, C[i][j][t]);   // entries all positive
  mx = wave_max(mx);
  int e; (void)frexpf(mx, &e);
  s = ldexpf(1.f, -e);
  return e;
}

// ---------- coherent partial barriers, sharded counters (one per 64B line) ----------
__device__ __forceinline__ void arrive(int* c){
  __syncthreads();
  if(threadIdx.x == 0){
    __threadfence();
    __hip_atomic_fetch_add(c, 1, __ATOMIC_RELEASE, __HIP_MEMORY_SCOPE_AGENT);
  }
}
__device__ __forceinline__ void wait_ge(int* c, int target){
  if(threadIdx.x == 0){
    while(__hip_atomic_load(c, __ATOMIC_ACQUIRE, __HIP_MEMORY_SCOPE_AGENT) < target)
      __builtin_amdgcn_s_sleep(2);
    __threadfence();
  }
  __syncthreads();
}

// ==================== single kernel: 256 blocks x 512 threads, 1 block/CU ====================
// XCD-LOCAL dataflow: block b processes seq chunk sig(b) = (b&15)*16 + (b>>4).
// Group g = {b : b&15 == g} covers CONTIGUOUS chunks g*16..g*16+15, and all its
// blocks share b mod 8 => same XCD under round-robin dispatch. Combine block g
// (blocks 0..15) is in the same class -> node reads hit local L2.
// Blocks 254,255: power iteration after phase A (parallel with combines).
// Block 0: combiner for group 0, then waits c2>=18 and runs the final 16->1 + contraction.
__global__ __launch_bounds__(512) void kall(const float* __restrict__ K, const int* __restrict__ seq,
                                            u16* __restrict__ Nbuf, u16* __restrict__ M2buf,
                                            int* __restrict__ Sarr, int* __restrict__ Earr,
                                            float* __restrict__ rhoR, float* __restrict__ rhoL,
                                            float* __restrict__ muv, int* __restrict__ bar,
                                            float* __restrict__ outp){
  __shared__ __align__(16) u16 Kl[8*4096];     // bf16 K (Zn swizzled)
  __shared__ __align__(16) u16 zones[8*4096];
  __shared__ __align__(16) u16 rhoZ[4096];
  __shared__ float redf[8];
  __shared__ int exps[8];
  __shared__ float sh_t2;
  __shared__ int sh_S;
  const int tid = threadIdx.x, lane = tid & 63, wave = tid >> 6, b = blockIdx.x;
  const int m16 = lane & 15, q = lane >> 4;
  const int sig = (b & 15)*16 + (b >> 4);      // transposed chunk index (XCD-local groups)
  u16* zw = zones + wave*4096;

  // stage K[wave] fp32 -> Kl (Zn swizzled); lane owns row = lane
#pragma unroll
  for(int g = 0; g < 8; g++){
    const float* p = K + (size_t)wave*4096 + lane*64 + g*8;
    float4 a = *(const float4*)p, c = *(const float4*)(p + 4);
    u32x4 u = { pack2bf(a.x,a.y), pack2bf(a.z,a.w), pack2bf(c.x,c.y), pack2bf(c.z,c.w) };
    *(short8*)(Kl + wave*4096 + lane*64 + ((g ^ (lane & 7)) << 3)) = __builtin_bit_cast(short8, u);
  }
  int sv = (lane < 8) ? seq[sig*64 + wave*8 + lane] : 0;
  __syncthreads();

  // ================= PHASE A (all 256 blocks): node sig = 64 seq-mats =================
  {
    int s0 = __shfl(sv, 0, 64);
    lds_transpose(Kl + s0*4096, zw, lane);
    f32x4 C[4][4];
    short8 Af[2][4];
#pragma unroll 1
    for(int j = 1; j < 8; j++){
      int sj = __shfl(sv, j, 64);
      ld_zn_frags(Kl + sj*4096, m16, q, Af);
      chain_step_A(Af, zw, lane, C, j < 7);
    }
    { float s; int e = norm_es(C, s);
      if(!(wave & 1)) write_CT_lds_s(zw, lane, C, s);   // even wave -> Zt
      else            scatter_C_rm(zw, lane, C, s);     // odd wave  -> Zn
      if(lane == 0) exps[wave] = e; }
    __syncthreads();
    if(wave < 4){                                  // combine L1
      short8 Aa[2][4]; f32x4 Y[4][4];
      ld_zn_frags(zones + (2*wave + 1)*4096, m16, q, Aa);
      bool e2 = !(wave & 1);
      chain_step_A(Aa, zones + 2*wave*4096, lane, Y, e2);
      if(!e2) scatter_C_rm(zones + 2*wave*4096, lane, Y, 1.f);
    }
    __syncthreads();
    if(wave < 2){                                  // combine L2
      short8 Aa[2][4]; f32x4 Y[4][4];
      ld_zn_frags(zones + (4*wave + 2)*4096, m16, q, Aa);
      chain_step_A(Aa, zones + 4*wave*4096, lane, Y, wave == 0);
      if(wave == 1) scatter_C_rm(zones + 4*4096, lane, Y, 1.f);
    }
    __syncthreads();
    if(wave == 0){                                 // combine L3 + norm
      short8 Aa[2][4]; f32x4 M[4][4];
      ld_zn_frags(zones + 4*4096, m16, q, Aa);
      chain_step_A(Aa, zones, lane, M, false);
      float sr; int er = norm_es(M, sr);
      scatter_C_rm(zones, lane, M, sr);
      if(lane == 0){
        int ss = er;
#pragma unroll
        for(int w = 0; w < 8; w++) ss += exps[w];
        Sarr[sig] = ss;
      }
    }
    __syncthreads();
    { int row = tid >> 3, c0 = (tid & 7)*8;
      *(short8*)(Nbuf + (size_t)sig*4096 + row*64 + c0) = lds_frag(zones, row, c0); }
  }
  arrive(bar + (b & 15)*16);                       // c1[group], sharded, XCD-local

  if(b >= 254){
    // ================= POWER (blocks 254=right, 255=left; parallel with combines) =================
    const bool left = (b == 255);
    short8 Kf[2][4];
    if(!left){
      ld_zn_frags(Kl + wave*4096, m16, q, Kf);
    } else {
#pragma unroll
      for(int ks = 0; ks < 2; ks++)
#pragma unroll
        for(int t = 0; t < 4; t++){
          short8 v;
#pragma unroll
          for(int j = 0; j < 8; j++) v[j] = (short)Kl[wave*4096 + swz(ks*32 + q*8 + j, t*16 + m16)];
          Kf[ks][t] = v;
        }
    }
    const int row = tid >> 3, k0 = (tid & 7)*8;
    const int rpos = row*64 + (((tid & 7) ^ (row & 7)) << 3);
    {
      short8 bb;
#pragma unroll
      for(int j = 0; j < 8; j++) bb[j] = (row == k0 + j) ? (short)f2bf(1.f/64.f) : (short)0;
      *(short8*)(rhoZ + rpos) = bb;
    }
    __syncthreads();
    const float S13 = 1.f/8192.f;        // fixed per-iter scale (lambda ~ 2^13)
#pragma unroll
    for(int it = 0; it < POWER_ITERS; it++){
      short8 Ar[2][4];
#pragma unroll
      for(int ks = 0; ks < 2; ks++)
#pragma unroll
        for(int t = 0; t < 4; t++) Ar[ks][t] = lds_frag(rhoZ, t*16 + m16, ks*32 + q*8);
      f32x4 C[4][4];
#pragma unroll
      for(int i = 0; i < 4; i++)
#pragma unroll
        for(int j = 0; j < 4; j++) C[i][j] = f32x4{0.f,0.f,0.f,0.f};
#pragma unroll
      for(int ks = 0; ks < 2; ks++)
#pragma unroll
        for(int i = 0; i < 4; i++)
#pragma unroll
          for(int j = 0; j < 4; j++)
            C[i][j] = mfma_bf16(Ar[ks][i], Kf[ks][j], C[i][j]);   // rho * Kdir^T
      write_CT_lds(zw, lane, C);
      short8 Bt[2][4];
#pragma unroll
      for(int ks = 0; ks < 2; ks++)
#pragma unroll
        for(int t = 0; t < 4; t++) Bt[ks][t] = lds_frag(zw, t*16 + m16, ks*32 + q*8);
#pragma unroll
      for(int i = 0; i < 4; i++)
#pragma unroll
        for(int j = 0; j < 4; j++) C[i][j] = f32x4{0.f,0.f,0.f,0.f};
#pragma unroll
      for(int ks = 0; ks < 2; ks++)
#pragma unroll
        for(int i = 0; i < 4; i++)
#pragma unroll
          for(int j = 0; j < 4; j++)
            C[i][j] = mfma_bf16(Kf[ks][i], Bt[ks][j], C[i][j]);   // Kdir * (..)^T
      write_CT_lds(zw, lane, C);
      __syncthreads();
      float v[8];
#pragma unroll
      for(int j2 = 0; j2 < 8; j2++) v[j2] = 0.f;
#pragma unroll
      for(int z = 0; z < 8; z++){
        short8 f = lds_frag(zones + z*4096, row, k0);
#pragma unroll
        for(int j2 = 0; j2 < 8; j2++) v[j2] += bf2f((u16)f[j2]);
      }
      if(it != POWER_ITERS - 1){
        u32x4 u = { pack2bf(v[0]*S13, v[1]*S13), pack2bf(v[2]*S13, v[3]*S13),
                    pack2bf(v[4]*S13, v[5]*S13), pack2bf(v[6]*S13, v[7]*S13) };
        *(short8*)(rhoZ + rpos) = __builtin_bit_cast(short8, u);
        __syncthreads();
      } else {
        float pd = (k0 <= row && row < k0 + 8) ? v[row - k0] : 0.f;
        for(int off = 32; off; off >>= 1) pd += __shfl_xor(pd, off, 64);
        if(lane == 0) redf[wave] = pd;
        __syncthreads();
        float tr = 0.f;
#pragma unroll
        for(int w = 0; w < 8; w++) tr += redf[w];
        float inv = 1.f/tr;
        float* ro = left ? rhoL : rhoR;
#pragma unroll
        for(int j2 = 0; j2 < 8; j2++) ro[row*64 + k0 + j2] = v[j2]*inv;
        u32x4 u = { pack2bf(v[0]*inv, v[1]*inv), pack2bf(v[2]*inv, v[3]*inv),
                    pack2bf(v[4]*inv, v[5]*inv), pack2bf(v[6]*inv, v[7]*inv) };
        *(short8*)(rhoZ + rpos) = __builtin_bit_cast(short8, u);   // normalized bf16 in LDS
        __syncthreads();
      }
    }
    if(left){
      // lambda = tr(rho_l * sum_a K_a K_a^T); wave a handles K_a
      short8 Ka[2][4];
      ld_zn_frags(Kl + wave*4096, m16, q, Ka);
      f32x4 G[4][4];
#pragma unroll
      for(int i = 0; i < 4; i++)
#pragma unroll
        for(int j = 0; j < 4; j++) G[i][j] = f32x4{0.f,0.f,0.f,0.f};
#pragma unroll
      for(int ks = 0; ks < 2; ks++)
#pragma unroll
        for(int i = 0; i < 4; i++)
#pragma unroll
          for(int j = 0; j < 4; j++)
            G[i][j] = mfma_bf16(Ka[ks][i], Ka[ks][j], G[i][j]);
      float lp = 0.f;
#pragma unroll
      for(int i = 0; i < 4; i++)
#pragma unroll
        for(int j = 0; j < 4; j++)
#pragma unroll
          for(int t = 0; t < 4; t++){
            int r = i*16 + q*4 + t, c = j*16 + m16;
            lp += G[i][j][t] * bf2f(rhoZ[swz(r, c)]);
          }
      for(int off = 32; off; off >>= 1) lp += __shfl_xor(lp, off, 64);
      if(lane == 0) redf[wave] = lp;
      __syncthreads();
      if(tid == 0){
        float m = 0.f;
#pragma unroll
        for(int w = 0; w < 8; w++) m += redf[w];
        muv[0] = m;
      }
    }
    arrive(bar + 256);                             // c2 (rho/mu published)
  }

  if(b < 16){
    // ================= COMBINE: group b's 16 nodes (XCD-local) -> M2buf[b] =================
    wait_ge(bar + b*16, 16);
    const int nb = b*16;
    short8 Af[2][4];
    f32x4 C[4][4];
    ld_bf16_frags(Nbuf + (size_t)(nb + 2*wave + 1)*4096, m16, q, Af);
    load_Pt_transpose(Nbuf + (size_t)(nb + 2*wave)*4096, zw, lane);
    chain_step_A(Af, zw, lane, C, false);
    { float s; int e = norm_es(C, s);
      if(!(wave & 1)) write_CT_lds_s(zw, lane, C, s);
      else            scatter_C_rm(zw, lane, C, s);
      if(lane == 0) exps[wave] = e; }
    __syncthreads();
    if(wave < 4){
      short8 Aa[2][4]; f32x4 Y[4][4];
      ld_zn_frags(zones + (2*wave + 1)*4096, m16, q, Aa);
      bool e2 = !(wave & 1);
      chain_step_A(Aa, zones + 2*wave*4096, lane, Y, e2);
      if(!e2) scatter_C_rm(zones + 2*wave*4096, lane, Y, 1.f);
    }
    __syncthreads();
    if(wave < 2){
      short8 Aa[2][4]; f32x4 Y[4][4];
      ld_zn_frags(zones + (4*wave + 2)*4096, m16, q, Aa);
      chain_step_A(Aa, zones + 4*wave*4096, lane, Y, wave == 0);
      if(wave == 1) scatter_C_rm(zones + 4*4096, lane, Y, 1.f);
    }
    __syncthreads();
    if(wave == 0){
      short8 Aa[2][4]; f32x4 M[4][4];
      ld_zn_frags(zones + 4*4096, m16, q, Aa);
      chain_step_A(Aa, zones, lane, M, false);
      float sr; int er = norm_es(M, sr);
      scatter_C_rm(zones, lane, M, sr);
      if(lane == 0){
        int ss = er;
#pragma unroll
        for(int w = 0; w < 8; w++) ss += exps[w];
        Earr[b] = ss;
      }
    }
    __syncthreads();
    { int row = tid >> 3, c0 = (tid & 7)*8;
      *(short8*)(M2buf + (size_t)b*4096 + row*64 + c0) = lds_frag(zones, row, c0); }
    arrive(bar + 256);                             // c2
  }

  if(b == 0){
    // ================= FINAL =================
    wait_ge(bar + 256, 18);                        // 16 combiners + 2 power blocks
    // pair round: wave w: X_w = M2[2w+1]*M2[2w]
    short8 Af[2][4];
    f32x4 C[4][4];
    ld_bf16_frags(M2buf + (size_t)(2*wave + 1)*4096, m16, q, Af);
    load_Pt_transpose(M2buf + (size_t)(2*wave)*4096, zw, lane);
    chain_step_A(Af, zw, lane, C, false);
    { float s; int e = norm_es(C, s);
      if(!(wave & 1)) write_CT_lds_s(zw, lane, C, s);
      else            scatter_C_rm(zw, lane, C, s);
      if(lane == 0) exps[wave] = e; }
    __syncthreads();
    // L1 (waves 0-3) + side jobs (waves 4,5,6)
    if(wave < 4){
      short8 Aa[2][4]; f32x4 Y[4][4];
      ld_zn_frags(zones + (2*wave + 1)*4096, m16, q, Aa);
      bool e2 = !(wave & 1);
      chain_step_A(Aa, zones + 2*wave*4096, lane, Y, e2);
      if(!e2) scatter_C_rm(zones + 2*wave*4096, lane, Y, 1.f);
    } else if(wave == 4){
      float t2 = 0.f;
      for(int j = 0; j < 64; j++){
        int idx = lane + 64*j;
        t2 += rhoR[idx] * rhoL[idx];
      }
      for(int off = 32; off; off >>= 1) t2 += __shfl_xor(t2, off, 64);
      if(lane == 0) sh_t2 = t2;
    } else if(wave == 5){
      int s = Sarr[lane] + Sarr[lane + 64] + Sarr[lane + 128] + Sarr[lane + 192];
      if(lane < 16) s += Earr[lane];
      for(int off = 32; off; off >>= 1) s += __shfl_xor(s, off, 64);
      if(lane == 0) sh_S = s;
    } else if(wave == 6){
      // rho_r fp32 -> rhoZ (Zn bf16; symmetric)
#pragma unroll
      for(int g = 0; g < 8; g++){
        const float* p = rhoR + lane*64 + g*8;
        float4 a = *(const float4*)p, c = *(const float4*)(p + 4);
        u32x4 u = { pack2bf(a.x,a.y), pack2bf(a.z,a.w), pack2bf(c.x,c.y), pack2bf(c.z,c.w) };
        *(short8*)(rhoZ + lane*64 + ((g ^ (lane & 7)) << 3)) = __builtin_bit_cast(short8, u);
      }
    }
    __syncthreads();
    // L2 (waves 0,1); wave2: rho_l -> zone3 (free after L1)
    if(wave < 2){
      short8 Aa[2][4]; f32x4 Y[4][4];
      ld_zn_frags(zones + (4*wave + 2)*4096, m16, q, Aa);
      chain_step_A(Aa, zones + 4*wave*4096, lane, Y, wave == 0);
      if(wave == 1) scatter_C_rm(zones + 4*4096, lane, Y, 1.f);
    } else if(wave == 2){
#pragma unroll
      for(int g = 0; g < 8; g++){
        const float* p = rhoL + lane*64 + g*8;
        float4 a = *(const float4*)p, c = *(const float4*)(p + 4);
        u32x4 u = { pack2bf(a.x,a.y), pack2bf(a.z,a.w), pack2bf(c.x,c.y), pack2bf(c.z,c.w) };
        *(short8*)(zones + 3*4096 + lane*64 + ((g ^ (lane & 7)) << 3)) = __builtin_bit_cast(short8, u);
      }
    }
    __syncthreads();
    // L3 + contraction (wave 0)
    if(wave == 0){
      short8 Aa[2][4];
      ld_zn_frags(zones + 4*4096, m16, q, Aa);
      chain_step_A(Aa, zones, lane, C, false);
      float sM; int eM = norm_es(C, sM);
      u16* Pm = zones + 1*4096;                    // free zone
      scatter_C_rm(Pm, lane, C, sM);               // M (Zn)

      // U = M * rho_r  (rho_r bf16 in rhoZ, symmetric) -> U^T in zone2
      short8 Ua[2][4], Ub[2][4];
      ld_zn_frags(Pm, m16, q, Ua);
      ld_zn_frags(rhoZ, m16, q, Ub);
#pragma unroll
      for(int i = 0; i < 4; i++)
#pragma unroll
        for(int j = 0; j < 4; j++) C[i][j] = f32x4{0.f,0.f,0.f,0.f};
#pragma unroll
      for(int ks = 0; ks < 2; ks++)
#pragma unroll
        for(int i = 0; i < 4; i++)
#pragma unroll
          for(int j = 0; j < 4; j++)
            C[i][j] = mfma_bf16(Ua[ks][i], Ub[ks][j], C[i][j]);
      write_CT_lds(zones + 2*4096, lane, C);

      // D2 = rho_l * U
      ld_zn_frags(zones + 3*4096, m16, q, Ua);
#pragma unroll
      for(int ks = 0; ks < 2; ks++)
#pragma unroll
        for(int t = 0; t < 4; t++) Ub[ks][t] = lds_frag(zones + 2*4096, t*16 + m16, ks*32 + q*8);
#pragma unroll
      for(int i = 0; i < 4; i++)
#pragma unroll
        for(int j = 0; j < 4; j++) C[i][j] = f32x4{0.f,0.f,0.f,0.f};
#pragma unroll
      for(int ks = 0; ks < 2; ks++)
#pragma unroll
        for(int i = 0; i < 4; i++)
#pragma unroll
          for(int j = 0; j < 4; j++)
            C[i][j] = mfma_bf16(Ua[ks][i], Ub[ks][j], C[i][j]);

      // t1 = sum_ij D2_ij * M_ij
      float part = 0.f;
#pragma unroll
      for(int i = 0; i < 4; i++)
#pragma unroll
        for(int j = 0; j < 4; j++)
#pragma unroll
          for(int t = 0; t < 4; t++){
            int r = i*16 + q*4 + t, c = j*16 + m16;
            part += C[i][j][t] * bf2f(Pm[swz(r, c)]);
          }
      for(int off = 32; off; off >>= 1) part += __shfl_xor(part, off, 64);
      if(lane == 0){
        double t1  = (double)part;
        double lam = (double)muv[0];
        double S   = (double)sh_S + eM;
#pragma unroll
        for(int w = 0; w < 8; w++) S += exps[w];
        double logp = 16384.0*log2(lam) - 2.0*S - log2(t1) + log2((double)sh_t2);
        outp[0] = (float)logp;
      }
    }
  }
}

// ---------- launch ----------
extern "C" void kernel_launch(void* const* d_in, const int* in_sizes, int n_in,
                              void* d_out, int out_size, void* d_ws, size_t ws_size,
                              hipStream_t stream) {
  const float* K  = (const float*)d_in[0];   // (8,64,64) fp32
  const int* seq  = (const int*)d_in[1];     // (16384,) int32
  char* ws = (char*)d_ws;
  u16*   Nbuf  = (u16*)(ws);                   // 256 * 8KB = 2 MB
  u16*   M2buf = (u16*)(ws + 2097152);         // 16 * 8KB = 128 KB
  int*   Sarr  = (int*)(ws + 2228224);         // 256 ints
  int*   Earr  = (int*)(ws + 2229248);         // 16 ints
  float* rhoR  = (float*)(ws + 2229760);       // 16 KB
  float* rhoL  = (float*)(ws + 2246144);       // 16 KB
  float* muv   = (float*)(ws + 2262528);       // 1 float
  int*   bar   = (int*)(ws + 2262592);         // c1[16] sharded (64B/line) + c2 at [256]

  hipMemsetAsync(bar, 0, (256 + 16)*4, stream);
  kall<<<256, 512, 0, stream>>>(K, seq, Nbuf, M2buf, Sarr, Earr, rhoR, rhoL, muv, bar,
                                (float*)d_out);
}

// Round 13
// 99.733 us; speedup vs baseline: 1.7202x; 1.0846x over previous
//
#include <hip/hip_runtime.h>

typedef unsigned short u16;
typedef unsigned int   u32;
typedef short  short8  __attribute__((ext_vector_type(8)));
typedef __bf16 bf16x8  __attribute__((ext_vector_type(8)));
typedef float  f32x4   __attribute__((ext_vector_type(4)));
typedef u32    u32x4   __attribute__((ext_vector_type(4)));

#define POWER_ITERS 3

// ---------- helpers ----------
__device__ __forceinline__ u16 f2bf(float f){ return __builtin_bit_cast(u16, (__bf16)f); }
__device__ __forceinline__ u32 pack2bf(float a, float b){
  return (u32)__builtin_bit_cast(u16, (__bf16)a) | ((u32)__builtin_bit_cast(u16, (__bf16)b) << 16);
}
__device__ __forceinline__ float bf2f(u16 h){ return __uint_as_float(((u32)h) << 16); }

// write-through agent-scope store: data visible at coherence point on retirement
// (no buffer_wbl2 needed on the release side)
__device__ __forceinline__ void st_u32(u32* p, u32 v){
  __hip_atomic_store(p, v, __ATOMIC_RELAXED, __HIP_MEMORY_SCOPE_AGENT);
}
__device__ __forceinline__ void st_f32(float* p, float v){
  __hip_atomic_store(p, v, __ATOMIC_RELAXED, __HIP_MEMORY_SCOPE_AGENT);
}
__device__ __forceinline__ void st_i32(int* p, int v){
  __hip_atomic_store(p, v, __ATOMIC_RELAXED, __HIP_MEMORY_SCOPE_AGENT);
}

__device__ __forceinline__ f32x4 mfma_bf16(short8 a, short8 b, f32x4 c){
  return __builtin_amdgcn_mfma_f32_16x16x32_bf16(
      __builtin_bit_cast(bf16x8, a), __builtin_bit_cast(bf16x8, b), c, 0, 0, 0);
}

// swizzled LDS address (u16 units) of element [row][k] of a 64x64 matrix
__device__ __forceinline__ int swz(int row, int k){
  return row*64 + ((((k >> 3) ^ (row & 7)) << 3) | (k & 7));
}
__device__ __forceinline__ short8 lds_frag(const u16* P, int row, int k0){
  int pos = (k0 >> 3) ^ (row & 7);
  return *(const short8*)(P + row*64 + pos*8);
}
__device__ __forceinline__ short8 g_frag(const u16* __restrict__ M, int row, int k0){
  return *(const short8*)(M + row*64 + k0);
}

// write C/D regs (matrix X) as X^T into swizzled LDS (Zt), scaled
__device__ __forceinline__ void write_CT_lds_s(u16* Pt, int lane, const f32x4 (&C)[4][4], float s){
  const int m16 = lane & 15, q = lane >> 4;
#pragma unroll
  for(int i = 0; i < 4; i++){
    const int r0 = i*16 + q*4;
#pragma unroll
    for(int j = 0; j < 4; j++){
      const int c = j*16 + m16;
      const int addr = c*64 + ((((r0 >> 3) ^ (c & 7)) << 3) | (r0 & 7));
      u32 lo = pack2bf(C[i][j][0]*s, C[i][j][1]*s);
      u32 hi = pack2bf(C[i][j][2]*s, C[i][j][3]*s);
      *(uint2*)(Pt + addr) = make_uint2(lo, hi);
    }
  }
}
__device__ __forceinline__ void write_CT_lds(u16* Pt, int lane, const f32x4 (&C)[4][4]){
  write_CT_lds_s(Pt, lane, C, 1.f);
}

// write C ROW-MAJOR swizzled (Zn), scaled — scalar scatter
__device__ __forceinline__ void scatter_C_rm(u16* Z, int lane, const f32x4 (&C)[4][4], float s){
  const int m16 = lane & 15, q = lane >> 4;
#pragma unroll
  for(int i = 0; i < 4; i++)
#pragma unroll
    for(int j = 0; j < 4; j++)
#pragma unroll
      for(int t = 0; t < 4; t++)
        Z[swz(i*16 + q*4 + t, j*16 + m16)] = f2bf(C[i][j][t]*s);
}

// C = A (regs) * P (Pt = Zt of P); optional writeback of C^T into Pt
__device__ __forceinline__ void chain_step_A(const short8 (&Af)[2][4], u16* Pt, int lane,
                                             f32x4 (&C)[4][4], bool wb){
  const int m16 = lane & 15, q = lane >> 4;
  short8 Bf[2][4];
#pragma unroll
  for(int ks = 0; ks < 2; ks++)
#pragma unroll
    for(int t = 0; t < 4; t++) Bf[ks][t] = lds_frag(Pt, t*16 + m16, ks*32 + q*8);
#pragma unroll
  for(int i = 0; i < 4; i++)
#pragma unroll
    for(int j = 0; j < 4; j++) C[i][j] = f32x4{0.f,0.f,0.f,0.f};
#pragma unroll
  for(int ks = 0; ks < 2; ks++)
#pragma unroll
    for(int i = 0; i < 4; i++)
#pragma unroll
      for(int j = 0; j < 4; j++)
        C[i][j] = mfma_bf16(Af[ks][i], Bf[ks][j], C[i][j]);
  if(wb) write_CT_lds(Pt, lane, C);
}

__device__ __forceinline__ void ld_zn_frags(const u16* Zn, int m16, int q, short8 (&Af)[2][4]){
#pragma unroll
  for(int ks = 0; ks < 2; ks++)
#pragma unroll
    for(int t = 0; t < 4; t++) Af[ks][t] = lds_frag(Zn, t*16 + m16, ks*32 + q*8);
}
__device__ __forceinline__ void ld_bf16_frags(const u16* __restrict__ M, int m16, int q, short8 (&Af)[2][4]){
#pragma unroll
  for(int ks = 0; ks < 2; ks++)
#pragma unroll
    for(int t = 0; t < 4; t++) Af[ks][t] = g_frag(M, t*16 + m16, ks*32 + q*8);
}

// P = N (global row-major bf16) -> Zt of P
__device__ __forceinline__ void load_Pt_transpose(const u16* __restrict__ N, u16* Pt, int lane){
#pragma unroll
  for(int g = 0; g < 8; g++){
    short8 v = *(const short8*)(N + lane*64 + g*8);
#pragma unroll
    for(int t = 0; t < 8; t++) Pt[swz(g*8 + t, lane)] = (u16)v[t];
  }
}
// Pt <- Zt of an LDS Zn zone
__device__ __forceinline__ void lds_transpose(const u16* Z, u16* Pt, int lane){
#pragma unroll
  for(int g = 0; g < 8; g++){
    short8 f = lds_frag(Z, lane, g*8);
#pragma unroll
    for(int j = 0; j < 8; j++) Pt[swz(g*8 + j, lane)] = (u16)f[j];
  }
}

__device__ __forceinline__ float wave_max(float mx){
  for(int off = 32; off; off >>= 1) mx = fmaxf(mx, __shfl_xor(mx, off, 64));
  return mx;
}
__device__ __forceinline__ int norm_es(const f32x4 (&C)[4][4], float& s){
  float mx = 0.f;
#pragma unroll
  for(int i = 0; i < 4; i++)
#pragma unroll
    for(int j = 0; j < 4; j++)
#pragma unroll
      for(int t = 0; t < 4; t++) mx = fmaxf(mx, C[i][j][t]);   // entries all positive
  mx = wave_max(mx);
  int e; (void)frexpf(mx, &e);
  s = ldexpf(1.f, -e);
  return e;
}

// ---------- fence-free barriers ----------
// producer payloads go out via write-through atomic stores (st_u32), so arrive needs
// NO __threadfence (no buffer_wbl2). __syncthreads drains vmcnt => stores complete.
__device__ __forceinline__ void arrive(int* c){
  __syncthreads();
  if(threadIdx.x == 0)
    __hip_atomic_fetch_add(c, 1, __ATOMIC_RELAXED, __HIP_MEMORY_SCOPE_AGENT);
}
// consumer: acquire poll (buffer_inv only — no writeback)
__device__ __forceinline__ void wait_ge(int* c, int target){
  if(threadIdx.x == 0){
    while(__hip_atomic_load(c, __ATOMIC_ACQUIRE, __HIP_MEMORY_SCOPE_AGENT) < target)
      __builtin_amdgcn_s_sleep(2);
  }
  __syncthreads();
}

// store a 64x64 node from LDS (Zn swizzled) to global via write-through dword stores
__device__ __forceinline__ void store_node_wt(const u16* Z, u16* __restrict__ out, int tid){
  int row = tid >> 3, c0 = (tid & 7)*8;
  short8 v = lds_frag(Z, row, c0);
  u32x4 uv = __builtin_bit_cast(u32x4, v);
  u32* p = (u32*)(out + row*64 + c0);
#pragma unroll
  for(int i = 0; i < 4; i++) st_u32(p + i, uv[i]);
}

// ==================== single kernel: 256 blocks x 512 threads, 1 block/CU ====================
// Block b processes seq chunk sig(b) = (b&15)*16 + (b>>4)  (XCD-local groups).
// Blocks 254,255: power iteration after phase A. Blocks 0..15: group combiners.
// Block 0: final 16->1 + contraction.
__global__ __launch_bounds__(512) void kall(const float* __restrict__ K, const int* __restrict__ seq,
                                            u16* __restrict__ Nbuf, u16* __restrict__ M2buf,
                                            int* __restrict__ Sarr, int* __restrict__ Earr,
                                            float* __restrict__ rhoR, float* __restrict__ rhoL,
                                            float* __restrict__ muv, int* __restrict__ bar,
                                            float* __restrict__ outp){
  __shared__ __align__(16) u16 Kl[8*4096];     // bf16 K (Zn swizzled)
  __shared__ __align__(16) u16 zones[8*4096];
  __shared__ __align__(16) u16 rhoZ[4096];
  __shared__ float redf[8];
  __shared__ int exps[8];
  __shared__ float sh_t2;
  __shared__ int sh_S;
  const int tid = threadIdx.x, lane = tid & 63, wave = tid >> 6, b = blockIdx.x;
  const int m16 = lane & 15, q = lane >> 4;
  const int sig = (b & 15)*16 + (b >> 4);
  u16* zw = zones + wave*4096;

  // stage K[wave] fp32 -> Kl (Zn swizzled); lane owns row = lane
#pragma unroll
  for(int g = 0; g < 8; g++){
    const float* p = K + (size_t)wave*4096 + lane*64 + g*8;
    float4 a = *(const float4*)p, c = *(const float4*)(p + 4);
    u32x4 u = { pack2bf(a.x,a.y), pack2bf(a.z,a.w), pack2bf(c.x,c.y), pack2bf(c.z,c.w) };
    *(short8*)(Kl + wave*4096 + lane*64 + ((g ^ (lane & 7)) << 3)) = __builtin_bit_cast(short8, u);
  }
  int sv = (lane < 8) ? seq[sig*64 + wave*8 + lane] : 0;
  __syncthreads();

  // ================= PHASE A (all 256 blocks): node sig = 64 seq-mats =================
  {
    int s0 = __shfl(sv, 0, 64);
    lds_transpose(Kl + s0*4096, zw, lane);
    f32x4 C[4][4];
    short8 Af[2][4];
#pragma unroll 1
    for(int j = 1; j < 8; j++){
      int sj = __shfl(sv, j, 64);
      ld_zn_frags(Kl + sj*4096, m16, q, Af);
      chain_step_A(Af, zw, lane, C, j < 7);
    }
    { float s; int e = norm_es(C, s);
      if(!(wave & 1)) write_CT_lds_s(zw, lane, C, s);   // even wave -> Zt
      else            scatter_C_rm(zw, lane, C, s);     // odd wave  -> Zn
      if(lane == 0) exps[wave] = e; }
    __syncthreads();
    if(wave < 4){                                  // combine L1
      short8 Aa[2][4]; f32x4 Y[4][4];
      ld_zn_frags(zones + (2*wave + 1)*4096, m16, q, Aa);
      bool e2 = !(wave & 1);
      chain_step_A(Aa, zones + 2*wave*4096, lane, Y, e2);
      if(!e2) scatter_C_rm(zones + 2*wave*4096, lane, Y, 1.f);
    }
    __syncthreads();
    if(wave < 2){                                  // combine L2
      short8 Aa[2][4]; f32x4 Y[4][4];
      ld_zn_frags(zones + (4*wave + 2)*4096, m16, q, Aa);
      chain_step_A(Aa, zones + 4*wave*4096, lane, Y, wave == 0);
      if(wave == 1) scatter_C_rm(zones + 4*4096, lane, Y, 1.f);
    }
    __syncthreads();
    if(wave == 0){                                 // combine L3 + norm
      short8 Aa[2][4]; f32x4 M[4][4];
      ld_zn_frags(zones + 4*4096, m16, q, Aa);
      chain_step_A(Aa, zones, lane, M, false);
      float sr; int er = norm_es(M, sr);
      scatter_C_rm(zones, lane, M, sr);
      if(lane == 0){
        int ss = er;
#pragma unroll
        for(int w = 0; w < 8; w++) ss += exps[w];
        st_i32(&Sarr[sig], ss);
      }
    }
    __syncthreads();
    store_node_wt(zones, Nbuf + (size_t)sig*4096, tid);
  }
  arrive(bar + (b & 15)*16);                       // c1[group], sharded

  if(b >= 254){
    // ================= POWER (254=right, 255=left; parallel with combines) =================
    const bool left = (b == 255);
    short8 Kf[2][4];
    if(!left){
      ld_zn_frags(Kl + wave*4096, m16, q, Kf);
    } else {
#pragma unroll
      for(int ks = 0; ks < 2; ks++)
#pragma unroll
        for(int t = 0; t < 4; t++){
          short8 v;
#pragma unroll
          for(int j = 0; j < 8; j++) v[j] = (short)Kl[wave*4096 + swz(ks*32 + q*8 + j, t*16 + m16)];
          Kf[ks][t] = v;
        }
    }
    const int row = tid >> 3, k0 = (tid & 7)*8;
    const int rpos = row*64 + (((tid & 7) ^ (row & 7)) << 3);
    {
      short8 bb;
#pragma unroll
      for(int j = 0; j < 8; j++) bb[j] = (row == k0 + j) ? (short)f2bf(1.f/64.f) : (short)0;
      *(short8*)(rhoZ + rpos) = bb;
    }
    __syncthreads();
    const float S13 = 1.f/8192.f;        // fixed per-iter scale (lambda ~ 2^13)
#pragma unroll
    for(int it = 0; it < POWER_ITERS; it++){
      short8 Ar[2][4];
#pragma unroll
      for(int ks = 0; ks < 2; ks++)
#pragma unroll
        for(int t = 0; t < 4; t++) Ar[ks][t] = lds_frag(rhoZ, t*16 + m16, ks*32 + q*8);
      f32x4 C[4][4];
#pragma unroll
      for(int i = 0; i < 4; i++)
#pragma unroll
        for(int j = 0; j < 4; j++) C[i][j] = f32x4{0.f,0.f,0.f,0.f};
#pragma unroll
      for(int ks = 0; ks < 2; ks++)
#pragma unroll
        for(int i = 0; i < 4; i++)
#pragma unroll
          for(int j = 0; j < 4; j++)
            C[i][j] = mfma_bf16(Ar[ks][i], Kf[ks][j], C[i][j]);   // rho * Kdir^T
      write_CT_lds(zw, lane, C);
      short8 Bt[2][4];
#pragma unroll
      for(int ks = 0; ks < 2; ks++)
#pragma unroll
        for(int t = 0; t < 4; t++) Bt[ks][t] = lds_frag(zw, t*16 + m16, ks*32 + q*8);
#pragma unroll
      for(int i = 0; i < 4; i++)
#pragma unroll
        for(int j = 0; j < 4; j++) C[i][j] = f32x4{0.f,0.f,0.f,0.f};
#pragma unroll
      for(int ks = 0; ks < 2; ks++)
#pragma unroll
        for(int i = 0; i < 4; i++)
#pragma unroll
          for(int j = 0; j < 4; j++)
            C[i][j] = mfma_bf16(Kf[ks][i], Bt[ks][j], C[i][j]);   // Kdir * (..)^T
      write_CT_lds(zw, lane, C);
      __syncthreads();
      float v[8];
#pragma unroll
      for(int j2 = 0; j2 < 8; j2++) v[j2] = 0.f;
#pragma unroll
      for(int z = 0; z < 8; z++){
        short8 f = lds_frag(zones + z*4096, row, k0);
#pragma unroll
        for(int j2 = 0; j2 < 8; j2++) v[j2] += bf2f((u16)f[j2]);
      }
      if(it != POWER_ITERS - 1){
        u32x4 u = { pack2bf(v[0]*S13, v[1]*S13), pack2bf(v[2]*S13, v[3]*S13),
                    pack2bf(v[4]*S13, v[5]*S13), pack2bf(v[6]*S13, v[7]*S13) };
        *(short8*)(rhoZ + rpos) = __builtin_bit_cast(short8, u);
        __syncthreads();
      } else {
        float pd = (k0 <= row && row < k0 + 8) ? v[row - k0] : 0.f;
        for(int off = 32; off; off >>= 1) pd += __shfl_xor(pd, off, 64);
        if(lane == 0) redf[wave] = pd;
        __syncthreads();
        float tr = 0.f;
#pragma unroll
        for(int w = 0; w < 8; w++) tr += redf[w];
        float inv = 1.f/tr;
        float* ro = left ? rhoL : rhoR;
#pragma unroll
        for(int j2 = 0; j2 < 8; j2++) st_f32(&ro[row*64 + k0 + j2], v[j2]*inv);
        u32x4 u = { pack2bf(v[0]*inv, v[1]*inv), pack2bf(v[2]*inv, v[3]*inv),
                    pack2bf(v[4]*inv, v[5]*inv), pack2bf(v[6]*inv, v[7]*inv) };
        *(short8*)(rhoZ + rpos) = __builtin_bit_cast(short8, u);   // normalized bf16 in LDS
        __syncthreads();
      }
    }
    if(left){
      // lambda = tr(rho_l * sum_a K_a K_a^T); wave a handles K_a
      short8 Ka[2][4];
      ld_zn_frags(Kl + wave*4096, m16, q, Ka);
      f32x4 G[4][4];
#pragma unroll
      for(int i = 0; i < 4; i++)
#pragma unroll
        for(int j = 0; j < 4; j++) G[i][j] = f32x4{0.f,0.f,0.f,0.f};
#pragma unroll
      for(int ks = 0; ks < 2; ks++)
#pragma unroll
        for(int i = 0; i < 4; i++)
#pragma unroll
          for(int j = 0; j < 4; j++)
            G[i][j] = mfma_bf16(Ka[ks][i], Ka[ks][j], G[i][j]);
      float lp = 0.f;
#pragma unroll
      for(int i = 0; i < 4; i++)
#pragma unroll
        for(int j = 0; j < 4; j++)
#pragma unroll
          for(int t = 0; t < 4; t++){
            int r = i*16 + q*4 + t, c = j*16 + m16;
            lp += G[i][j][t] * bf2f(rhoZ[swz(r, c)]);
          }
      for(int off = 32; off; off >>= 1) lp += __shfl_xor(lp, off, 64);
      if(lane == 0) redf[wave] = lp;
      __syncthreads();
      if(tid == 0){
        float m = 0.f;
#pragma unroll
        for(int w = 0; w < 8; w++) m += redf[w];
        st_f32(muv, m);
      }
    }
    arrive(bar + 256);                             // c2 (rho/mu published, write-through)
  }

  if(b < 16){
    // ================= COMBINE: group b's 16 nodes -> M2buf[b] =================
    wait_ge(bar + b*16, 16);
    const int nb = b*16;
    short8 Af[2][4];
    f32x4 C[4][4];
    ld_bf16_frags(Nbuf + (size_t)(nb + 2*wave + 1)*4096, m16, q, Af);
    load_Pt_transpose(Nbuf + (size_t)(nb + 2*wave)*4096, zw, lane);
    chain_step_A(Af, zw, lane, C, false);
    { float s; int e = norm_es(C, s);
      if(!(wave & 1)) write_CT_lds_s(zw, lane, C, s);
      else            scatter_C_rm(zw, lane, C, s);
      if(lane == 0) exps[wave] = e; }
    __syncthreads();
    if(wave < 4){
      short8 Aa[2][4]; f32x4 Y[4][4];
      ld_zn_frags(zones + (2*wave + 1)*4096, m16, q, Aa);
      bool e2 = !(wave & 1);
      chain_step_A(Aa, zones + 2*wave*4096, lane, Y, e2);
      if(!e2) scatter_C_rm(zones + 2*wave*4096, lane, Y, 1.f);
    }
    __syncthreads();
    if(wave < 2){
      short8 Aa[2][4]; f32x4 Y[4][4];
      ld_zn_frags(zones + (4*wave + 2)*4096, m16, q, Aa);
      chain_step_A(Aa, zones + 4*wave*4096, lane, Y, wave == 0);
      if(wave == 1) scatter_C_rm(zones + 4*4096, lane, Y, 1.f);
    }
    __syncthreads();
    if(wave == 0){
      short8 Aa[2][4]; f32x4 M[4][4];
      ld_zn_frags(zones + 4*4096, m16, q, Aa);
      chain_step_A(Aa, zones, lane, M, false);
      float sr; int er = norm_es(M, sr);
      scatter_C_rm(zones, lane, M, sr);
      if(lane == 0){
        int ss = er;
#pragma unroll
        for(int w = 0; w < 8; w++) ss += exps[w];
        st_i32(&Earr[b], ss);
      }
    }
    __syncthreads();
    store_node_wt(zones, M2buf + (size_t)b*4096, tid);
    arrive(bar + 256);                             // c2
  }

  if(b == 0){
    // ================= FINAL =================
    wait_ge(bar + 256, 18);                        // 16 combiners + 2 power blocks
    short8 Af[2][4];
    f32x4 C[4][4];
    ld_bf16_frags(M2buf + (size_t)(2*wave + 1)*4096, m16, q, Af);
    load_Pt_transpose(M2buf + (size_t)(2*wave)*4096, zw, lane);
    chain_step_A(Af, zw, lane, C, false);
    { float s; int e = norm_es(C, s);
      if(!(wave & 1)) write_CT_lds_s(zw, lane, C, s);
      else            scatter_C_rm(zw, lane, C, s);
      if(lane == 0) exps[wave] = e; }
    __syncthreads();
    // L1 (waves 0-3) + side jobs (waves 4,5,6)
    if(wave < 4){
      short8 Aa[2][4]; f32x4 Y[4][4];
      ld_zn_frags(zones + (2*wave + 1)*4096, m16, q, Aa);
      bool e2 = !(wave & 1);
      chain_step_A(Aa, zones + 2*wave*4096, lane, Y, e2);
      if(!e2) scatter_C_rm(zones + 2*wave*4096, lane, Y, 1.f);
    } else if(wave == 4){
      float t2 = 0.f;
      for(int j = 0; j < 64; j++){
        int idx = lane + 64*j;
        t2 += rhoR[idx] * rhoL[idx];
      }
      for(int off = 32; off; off >>= 1) t2 += __shfl_xor(t2, off, 64);
      if(lane == 0) sh_t2 = t2;
    } else if(wave == 5){
      int s = Sarr[lane] + Sarr[lane + 64] + Sarr[lane + 128] + Sarr[lane + 192];
      if(lane < 16) s += Earr[lane];
      for(int off = 32; off; off >>= 1) s += __shfl_xor(s, off, 64);
      if(lane == 0) sh_S = s;
    } else if(wave == 6){
      // rho_r fp32 -> rhoZ (Zn bf16; symmetric)
#pragma unroll
      for(int g = 0; g < 8; g++){
        const float* p = rhoR + lane*64 + g*8;
        float4 a = *(const float4*)p, c = *(const float4*)(p + 4);
        u32x4 u = { pack2bf(a.x,a.y), pack2bf(a.z,a.w), pack2bf(c.x,c.y), pack2bf(c.z,c.w) };
        *(short8*)(rhoZ + lane*64 + ((g ^ (lane & 7)) << 3)) = __builtin_bit_cast(short8, u);
      }
    }
    __syncthreads();
    // L2 (waves 0,1); wave2: rho_l -> zone3 (free after L1)
    if(wave < 2){
      short8 Aa[2][4]; f32x4 Y[4][4];
      ld_zn_frags(zones + (4*wave + 2)*4096, m16, q, Aa);
      chain_step_A(Aa, zones + 4*wave*4096, lane, Y, wave == 0);
      if(wave == 1) scatter_C_rm(zones + 4*4096, lane, Y, 1.f);
    } else if(wave == 2){
#pragma unroll
      for(int g = 0; g < 8; g++){
        const float* p = rhoL + lane*64 + g*8;
        float4 a = *(const float4*)p, c = *(const float4*)(p + 4);
        u32x4 u = { pack2bf(a.x,a.y), pack2bf(a.z,a.w), pack2bf(c.x,c.y), pack2bf(c.z,c.w) };
        *(short8*)(zones + 3*4096 + lane*64 + ((g ^ (lane & 7)) << 3)) = __builtin_bit_cast(short8, u);
      }
    }
    __syncthreads();
    // L3 + contraction (wave 0)
    if(wave == 0){
      short8 Aa[2][4];
      ld_zn_frags(zones + 4*4096, m16, q, Aa);
      chain_step_A(Aa, zones, lane, C, false);
      float sM; int eM = norm_es(C, sM);
      u16* Pm = zones + 1*4096;                    // free zone
      scatter_C_rm(Pm, lane, C, sM);               // M (Zn)

      // U = M * rho_r -> U^T in zone2
      short8 Ua[2][4], Ub[2][4];
      ld_zn_frags(Pm, m16, q, Ua);
      ld_zn_frags(rhoZ, m16, q, Ub);
#pragma unroll
      for(int i = 0; i < 4; i++)
#pragma unroll
        for(int j = 0; j < 4; j++) C[i][j] = f32x4{0.f,0.f,0.f,0.f};
#pragma unroll
      for(int ks = 0; ks < 2; ks++)
#pragma unroll
        for(int i = 0; i < 4; i++)
#pragma unroll
          for(int j = 0; j < 4; j++)
            C[i][j] = mfma_bf16(Ua[ks][i], Ub[ks][j], C[i][j]);
      write_CT_lds(zones + 2*4096, lane, C);

      // D2 = rho_l * U
      ld_zn_frags(zones + 3*4096, m16, q, Ua);
#pragma unroll
      for(int ks = 0; ks < 2; ks++)
#pragma unroll
        for(int t = 0; t < 4; t++) Ub[ks][t] = lds_frag(zones + 2*4096, t*16 + m16, ks*32 + q*8);
#pragma unroll
      for(int i = 0; i < 4; i++)
#pragma unroll
        for(int j = 0; j < 4; j++) C[i][j] = f32x4{0.f,0.f,0.f,0.f};
#pragma unroll
      for(int ks = 0; ks < 2; ks++)
#pragma unroll
        for(int i = 0; i < 4; i++)
#pragma unroll
          for(int j = 0; j < 4; j++)
            C[i][j] = mfma_bf16(Ua[ks][i], Ub[ks][j], C[i][j]);

      // t1 = sum_ij D2_ij * M_ij
      float part = 0.f;
#pragma unroll
      for(int i = 0; i < 4; i++)
#pragma unroll
        for(int j = 0; j < 4; j++)
#pragma unroll
          for(int t = 0; t < 4; t++){
            int r = i*16 + q*4 + t, c = j*16 + m16;
            part += C[i][j][t] * bf2f(Pm[swz(r, c)]);
          }
      for(int off = 32; off; off >>= 1) part += __shfl_xor(part, off, 64);
      if(lane == 0){
        double t1  = (double)part;
        double lam = (double)muv[0];
        double S   = (double)sh_S + eM;
#pragma unroll
        for(int w = 0; w < 8; w++) S += exps[w];
        double logp = 16384.0*log2(lam) - 2.0*S - log2(t1) + log2((double)sh_t2);
        outp[0] = (float)logp;
      }
    }
  }
}

// ---------- launch ----------
extern "C" void kernel_launch(void* const* d_in, const int* in_sizes, int n_in,
                              void* d_out, int out_size, void* d_ws, size_t ws_size,
                              hipStream_t stream) {
  const float* K  = (const float*)d_in[0];   // (8,64,64) fp32
  const int* seq  = (const int*)d_in[1];     // (16384,) int32
  char* ws = (char*)d_ws;
  u16*   Nbuf  = (u16*)(ws);                   // 256 * 8KB = 2 MB
  u16*   M2buf = (u16*)(ws + 2097152);         // 16 * 8KB = 128 KB
  int*   Sarr  = (int*)(ws + 2228224);         // 256 ints
  int*   Earr  = (int*)(ws + 2229248);         // 16 ints
  float* rhoR  = (float*)(ws + 2229760);       // 16 KB
  float* rhoL  = (float*)(ws + 2246144);       // 16 KB
  float* muv   = (float*)(ws + 2262528);       // 1 float
  int*   bar   = (int*)(ws + 2262592);         // c1[16] sharded (64B/line) + c2 at [256]

  hipMemsetAsync(bar, 0, (256 + 16)*4, stream);
  kall<<<256, 512, 0, stream>>>(K, seq, Nbuf, M2buf, Sarr, Earr, rhoR, rhoL, muv, bar,
                                (float*)d_out);
}